// Round 3
// baseline (234.797 us; speedup 1.0000x reference)
//
#include <hip/hip_runtime.h>
#include <math.h>

#define NIMG 96
#define NSLOT 1024
#define RES_INV (1.0f / 262144.0f)   // 1 / (512*512)

// exact fmodf(v+1,2)-1 for our magnitude range (Sterbenz-exact subtraction)
__device__ __forceinline__ float wrap1(float v) {
  float t = v + 1.0f;
  return t - 2.0f * truncf(t * 0.5f) - 1.0f;
}
__device__ __forceinline__ int bin_of(float v) {
  float b = floorf((v + 1.0f) * 128.0f);
  b = fminf(fmaxf(b, 0.0f), 255.0f);
  return (int)b;
}

// ---------------- Kernel A: x-lifting, register + shuffle, 1 wave = 1 row ---
// src: (NIMG,H,2*W2). xe_out: (NIMG,H,W2). P = pairs per lane (W2 = 64*P, or
// P==1 with lane<W2 masking for W2<64).
template<int P>
__global__ void __launch_bounds__(256) klift_x_reg(
    const float* __restrict__ src, float* __restrict__ xe_out,
    const float* __restrict__ kpx, const float* __restrict__ kux,
    const float* __restrict__ kcx, const float* __restrict__ krx,
    int H, int W2, int do_img,
    double* __restrict__ partial,
    unsigned* __restrict__ hist_img, unsigned* __restrict__ hist_delta)
{
  __shared__ unsigned shi[256];
  __shared__ unsigned shd[256];
  const int t = threadIdx.x, w = t >> 6, lane = t & 63;
  const int img = blockIdx.y;
  const int r = blockIdx.x * 4 + w;
  shd[t] = 0;
  if (do_img) shi[t] = 0;
  __syncthreads();

  const bool act = (P > 1) || (lane < W2);

  const float* rowp = src + ((size_t)img * H + r) * (size_t)(2 * W2);
  float e[P], o[P];
  if (P == 4) {
    float4 v0 = *(const float4*)(rowp + lane * 8);
    float4 v1 = *(const float4*)(rowp + lane * 8 + 4);
    e[0] = v0.x; o[0] = v0.y; e[1] = v0.z; o[1] = v0.w;
    e[P > 2 ? 2 : 0] = v1.x; o[P > 2 ? 2 : 0] = v1.y;
    e[P > 3 ? 3 : 0] = v1.z; o[P > 3 ? 3 : 0] = v1.w;
  } else if (P == 2) {
    float4 v0 = *(const float4*)(rowp + lane * 4);
    e[0] = v0.x; o[0] = v0.y; e[P > 1 ? 1 : 0] = v0.z; o[P > 1 ? 1 : 0] = v0.w;
  } else {
    if (act) { float2 v = *(const float2*)(rowp + lane * 2); e[0] = v.x; o[0] = v.y; }
    else { e[0] = 0.f; o[0] = 0.f; }
  }

  float sqi = 0.f;
  if (do_img) {
#pragma unroll
    for (int j = 0; j < P; j++) {
      sqi += e[j] * e[j] + o[j] * o[j];
      atomicAdd(&shi[bin_of(e[j])], 1u);
      atomicAdd(&shi[bin_of(o[j])], 1u);
    }
  }

  const float px0 = kpx[0], px1 = kpx[1], px2 = kpx[2];
  const float ux0 = kux[0], ux1 = kux[1], ux2 = kux[2];
  const float cx0 = kcx[0], cx1 = kcx[1], cx2 = kcx[2];
  const float rx0 = krx[0], rx1 = krx[1], rx2 = krx[2];

  auto stepm = [&](float (&d)[P], float (&s)[P], float k0, float k1, float k2, float sgn) {
    float L = __shfl_up(s[P - 1], 1); if (lane == 0) L = 0.f;
    float R = __shfl_down(s[0], 1);   if (lane == 63) R = 0.f;
    float prev = L;
#pragma unroll
    for (int j = 0; j < P; j++) {
      float nxt = (j == P - 1) ? R : s[(j + 1) < P ? (j + 1) : 0];
      d[j] += sgn * (k0 * prev + k1 * s[j] + k2 * nxt);
      prev = s[j];
    }
    if (P == 1 && !act) d[0] = 0.f;   // keep zero padding beyond W2
  };

  stepm(o, e, px0, px1, px2, -1.f);
  stepm(e, o, ux0, ux1, ux2,  1.f);
  stepm(o, e, cx0, cx1, cx2, -1.f);
  stepm(e, o, rx0, rx1, rx2,  1.f);

  float* orow = xe_out + ((size_t)img * H + r) * (size_t)W2;
  if (P == 4) {
    *(float4*)(orow + lane * 4) =
        make_float4(e[0], e[P > 1 ? 1 : 0], e[P > 2 ? 2 : 0], e[P > 3 ? 3 : 0]);
  } else if (P == 2) {
    *(float2*)(orow + lane * 2) = make_float2(e[0], e[P > 1 ? 1 : 0]);
  } else if (act) {
    orow[lane] = e[0];
  }

  float sqd = 0.f;
  if (act) {
#pragma unroll
    for (int j = 0; j < P; j++) {
      float d = wrap1(o[j]);
      sqd += d * d;
      if (d >= -1.f && d <= 1.f) atomicAdd(&shd[bin_of(d)], 1u);
    }
  }

  for (int off = 32; off; off >>= 1) {
    sqd += __shfl_down(sqd, off);
    if (do_img) sqi += __shfl_down(sqi, off);
  }
  if (lane == 0) {
    const int bid = blockIdx.x + blockIdx.y * gridDim.x;
    const int slot = (bid * 4 + w) & (NSLOT - 1);
    atomicAdd(&partial[NSLOT + slot], (double)sqd);
    if (do_img) atomicAdd(&partial[slot], (double)sqi);
  }
  __syncthreads();
  unsigned hd = shd[t];
  if (hd) atomicAdd(&hist_delta[img * 256 + t], hd);
  if (do_img) {
    unsigned hi = shi[t];
    if (hi) atomicAdd(&hist_img[img * 256 + t], hi);
  }
}

// ---------------- Kernel B: y-lifting, streaming register pipeline ---------
// xe: (NIMG,2*H2,W2) -> ye_out: (NIMG,H2,W2). lane=column, CPT columns/lane.
// Software pipeline: a=yo', b=ye', g=yo'', f=ye'' at lags 1..4. Segment
// [r0,r0+SEG) with 4-row warm-up.
template<int CPT>
__global__ void __launch_bounds__(64) klift_y_reg(
    const float* __restrict__ xe, float* __restrict__ ye_out,
    const float* __restrict__ kpy, const float* __restrict__ kuy,
    const float* __restrict__ kcy, const float* __restrict__ kry,
    int H2, int W2, int SEG, int use_uy, int add_ye,
    double* __restrict__ partial, unsigned* __restrict__ hist_delta)
{
  __shared__ unsigned shd[256];
  const int lane = threadIdx.x;
  const int img = blockIdx.z;
  const int r0 = blockIdx.y * SEG;
  const int c0 = blockIdx.x * (CPT * 64);
  for (int i = lane; i < 256; i += 64) shd[i] = 0;
  __syncthreads();

  const float py0 = kpy[0], py1 = kpy[1], py2 = kpy[2];
  const float uy0 = kuy[0], uy1 = kuy[1], uy2 = kuy[2];
  const float cy0 = kcy[0], cy1 = kcy[1], cy2 = kcy[2];
  const float ry0 = kry[0], ry1 = kry[1], ry2 = kry[2];

  const float* in[CPT];
  float* outp[CPT];
  bool act[CPT];
#pragma unroll
  for (int u = 0; u < CPT; u++) {
    int col = c0 + u * 64 + lane;
    act[u] = col < W2;
    if (!act[u]) col = 0;
    in[u]  = xe + (size_t)img * (2 * H2) * W2 + col;
    outp[u] = ye_out + (size_t)img * H2 * W2 + col;
  }

  float eP2[CPT], eP1[CPT], oP1[CPT], aP2[CPT], aP1[CPT];
  float bP2[CPT], bP1[CPT], gP2[CPT], gP1[CPT];
#pragma unroll
  for (int u = 0; u < CPT; u++) {
    eP2[u] = eP1[u] = oP1[u] = aP2[u] = aP1[u] = 0.f;
    bP2[u] = bP1[u] = gP2[u] = gP1[u] = 0.f;
  }

  const int rend = (r0 + SEG < H2) ? r0 + SEG : H2;
  const int rbeg = (r0 >= 4) ? r0 - 4 : 0;
  float sqd = 0.f;

  for (int r = rbeg; r <= rend + 3; ++r) {
    float eN[CPT], oN[CPT];
    const bool ld = (r < H2);
#pragma unroll
    for (int u = 0; u < CPT; u++) {
      if (ld && act[u]) {
        const float* p = in[u] + (size_t)(2 * r) * W2;
        eN[u] = p[0];
        oN[u] = p[W2];
      } else { eN[u] = 0.f; oN[u] = 0.f; }
    }
    const int ia = r - 1, ib = r - 2, ig = r - 3, io = r - 4;
    const bool va = (ia >= 0) && (ia < H2);
    const bool vb = (ib >= 0) && (ib < H2);
    const bool vg = (ig >= 0) && (ig < H2);
    const bool vo = (io >= 0) && (io < H2);
    const bool sg = (ig >= r0) && (ig < rend);
    const bool so = (io >= r0) && (io < rend);
#pragma unroll
    for (int u = 0; u < CPT; u++) {
      float aN = va ? (oP1[u] - (py0 * eP2[u] + py1 * eP1[u] + py2 * eN[u])) : 0.f;
      float bN = vb ? (eP2[u] + (use_uy ? (uy0 * aP2[u] + uy1 * aP1[u] + uy2 * aN) : 0.f)) : 0.f;
      float gN = vg ? (aP2[u] - (cy0 * bP2[u] + cy1 * bP1[u] + cy2 * bN)) : 0.f;
      float fN = vo ? (bP2[u] + (ry0 * gP2[u] + ry1 * gP1[u] + ry2 * gN)) : 0.f;
      if (act[u]) {
        if (sg) {
          float d = wrap1(gN);
          sqd += d * d;
          if (d >= -1.f && d <= 1.f) atomicAdd(&shd[bin_of(d)], 1u);
        }
        if (so) {
          outp[u][(size_t)io * W2] = fN;
          if (add_ye) {
            float d2 = wrap1(fN);
            sqd += d2 * d2;
            if (d2 >= -1.f && d2 <= 1.f) atomicAdd(&shd[bin_of(d2)], 1u);
          }
        }
      }
      eP2[u] = eP1[u]; eP1[u] = eN[u]; oP1[u] = oN[u];
      aP2[u] = aP1[u]; aP1[u] = aN;
      bP2[u] = bP1[u]; bP1[u] = bN;
      gP2[u] = gP1[u]; gP1[u] = gN;
    }
  }

  for (int off = 32; off; off >>= 1) sqd += __shfl_down(sqd, off);
  if (lane == 0) {
    const int bid = blockIdx.x + gridDim.x * (blockIdx.y + gridDim.y * blockIdx.z);
    atomicAdd(&partial[NSLOT + (bid & (NSLOT - 1))], (double)sqd);
  }
  __syncthreads();
  for (int i = lane; i < 256; i += 64) {
    unsigned hd = shd[i];
    if (hd) atomicAdd(&hist_delta[img * 256 + i], hd);
  }
}

// ---------------- Final reduction: entropies + losses -----------------------
__global__ void __launch_bounds__(256) kfinal(
    const double* __restrict__ partial,
    const unsigned* __restrict__ hist_img,
    const unsigned* __restrict__ hist_delta,
    float* __restrict__ out)
{
  __shared__ double sI[256], sD[256], sPi[256], sPd[256];
  const int t = threadIdx.x;
  double entI = 0.0, entD = 0.0;
  for (int img = 0; img < NIMG; ++img) {
    unsigned ci = hist_img[img * 256 + t];
    if (ci) { float p = (float)ci * RES_INV; entI += (double)(-p * log2f(p)); }
    unsigned cd = hist_delta[img * 256 + t];
    if (cd) { float p = (float)cd * RES_INV; entD += (double)(-p * log2f(p)); }
  }
  double pi = 0.0, pd = 0.0;
  for (int s = t; s < NSLOT; s += 256) {
    pi += partial[s];
    pd += partial[NSLOT + s];
  }
  sI[t] = entI; sD[t] = entD; sPi[t] = pi; sPd[t] = pd;
  __syncthreads();
  for (int s = 128; s; s >>= 1) {
    if (t < s) {
      sI[t] += sI[t + s]; sD[t] += sD[t + s];
      sPi[t] += sPi[t + s]; sPd[t] += sPd[t + s];
    }
    __syncthreads();
  }
  if (t == 0) {
    const double tot = (double)NIMG * 262144.0;
    out[0] = (float)(255.0 * sqrt(sPd[0] / tot));  // loss1 (deltas)
    out[1] = (float)(255.0 * sqrt(sPi[0] / tot));  // loss0 (img)
    out[2] = (float)(sI[0] / (8.0 * NIMG));        // invCR0
    out[3] = (float)(sD[0] / (8.0 * NIMG));        // invCR1
  }
}

extern "C" void kernel_launch(void* const* d_in, const int* in_sizes, int n_in,
                              void* d_out, int out_size, void* d_ws, size_t ws_size,
                              hipStream_t stream)
{
  const float* x  = (const float*)d_in[0];
  const float* px = (const float*)d_in[1];
  const float* ux = (const float*)d_in[2];
  const float* cx = (const float*)d_in[3];
  const float* rx = (const float*)d_in[4];
  const float* py = (const float*)d_in[5];
  const float* uy = (const float*)d_in[6];
  const float* cy = (const float*)d_in[7];
  const float* ry = (const float*)d_in[8];
  float* out = (float*)d_out;

  char* ws = (char*)d_ws;
  double*   partial    = (double*)ws;
  unsigned* hist_img   = (unsigned*)(ws + 2 * NSLOT * 8);
  unsigned* hist_delta = (unsigned*)(ws + 2 * NSLOT * 8 + NIMG * 256 * 4);
  float* buf0 = (float*)(ws + (1 << 18));                        // xe, <=48MB
  float* buf1 = (float*)(ws + (1 << 18) + ((size_t)48 << 20));   // ye, <=24MB

  hipMemsetAsync(ws, 0, 2 * NSLOT * 8 + 2 * NIMG * 256 * 4, stream);

  const float* cur = x;
  for (int lvl = 0; lvl < 5; ++lvl) {
    const int H = 512 >> lvl, W2 = 256 >> lvl, H2 = H >> 1;

    dim3 gA(H / 4, NIMG);
    if (W2 >= 256)
      klift_x_reg<4><<<gA, 256, 0, stream>>>(cur, buf0, px, ux, cx, rx, H, W2,
                                             lvl == 0, partial, hist_img, hist_delta);
    else if (W2 >= 128)
      klift_x_reg<2><<<gA, 256, 0, stream>>>(cur, buf0, px, ux, cx, rx, H, W2,
                                             lvl == 0, partial, hist_img, hist_delta);
    else
      klift_x_reg<1><<<gA, 256, 0, stream>>>(cur, buf0, px, ux, cx, rx, H, W2,
                                             lvl == 0, partial, hist_img, hist_delta);

    const int CPT = (W2 >= 128) ? 2 : 1;
    int SEG = (lvl == 0) ? 64 : 32;
    if (SEG > H2) SEG = H2;
    const int gridx = (W2 / (CPT * 64)) > 0 ? (W2 / (CPT * 64)) : 1;
    const int nseg = (H2 + SEG - 1) / SEG;
    dim3 gB(gridx, nseg, NIMG);
    if (CPT == 2)
      klift_y_reg<2><<<gB, 64, 0, stream>>>(buf0, buf1, py, uy, cy, ry, H2, W2,
                                            SEG, lvl < 2, lvl == 4, partial, hist_delta);
    else
      klift_y_reg<1><<<gB, 64, 0, stream>>>(buf0, buf1, py, uy, cy, ry, H2, W2,
                                            SEG, lvl < 2, lvl == 4, partial, hist_delta);
    cur = buf1;
  }
  kfinal<<<1, 256, 0, stream>>>(partial, hist_img, hist_delta, out);
}

// Round 4
// 148.117 us; speedup vs baseline: 1.5852x; 1.5852x over previous
//
#include <hip/hip_runtime.h>
#include <math.h>

#define NIMG 96
#define NSLOT 1024
#define RES_INV (1.0f / 262144.0f)   // 1 / (512*512)

// exact fmod(v+1,2)-1 for our range
__device__ __forceinline__ float wrap1(float v) {
  float t = v + 1.0f;
  return t - 2.0f * truncf(t * 0.5f) - 1.0f;
}
__device__ __forceinline__ int bin_of(float v) {
  float b = floorf((v + 1.0f) * 128.0f);
  b = fminf(fmaxf(b, 0.0f), 255.0f);
  return (int)b;
}

// ---------------- Kernel A: x-lifting, register + shuffle, 1 wave = 1 row ---
// src: (NIMG,H,2*W2). xe_out: (NIMG,H,W2). P = pairs per lane (W2 = 64*P).
template<int P>
__global__ void __launch_bounds__(256) klift_x_reg(
    const float* __restrict__ src, float* __restrict__ xe_out,
    const float* __restrict__ kpx, const float* __restrict__ kux,
    const float* __restrict__ kcx, const float* __restrict__ krx,
    int H, int W2, int do_img,
    double* __restrict__ partial,
    unsigned* __restrict__ hist_img, unsigned* __restrict__ hist_delta)
{
  __shared__ unsigned shi[256];
  __shared__ unsigned shd[256];
  const int t = threadIdx.x, w = t >> 6, lane = t & 63;
  const int img = blockIdx.y;
  const int r = blockIdx.x * 4 + w;
  shd[t] = 0;
  if (do_img) shi[t] = 0;
  __syncthreads();

  const float* rowp = src + ((size_t)img * H + r) * (size_t)(2 * W2);
  float e[P], o[P];
  if (P == 4) {
    float4 v0 = *(const float4*)(rowp + lane * 8);
    float4 v1 = *(const float4*)(rowp + lane * 8 + 4);
    e[0] = v0.x; o[0] = v0.y; e[P > 1 ? 1 : 0] = v0.z; o[P > 1 ? 1 : 0] = v0.w;
    e[P > 2 ? 2 : 0] = v1.x; o[P > 2 ? 2 : 0] = v1.y;
    e[P > 3 ? 3 : 0] = v1.z; o[P > 3 ? 3 : 0] = v1.w;
  } else {
    float4 v0 = *(const float4*)(rowp + lane * 4);
    e[0] = v0.x; o[0] = v0.y; e[P > 1 ? 1 : 0] = v0.z; o[P > 1 ? 1 : 0] = v0.w;
  }

  float sqi = 0.f;
  if (do_img) {
#pragma unroll
    for (int j = 0; j < P; j++) {
      sqi += e[j] * e[j] + o[j] * o[j];
      atomicAdd(&shi[bin_of(e[j])], 1u);
      atomicAdd(&shi[bin_of(o[j])], 1u);
    }
  }

  const float px0 = kpx[0], px1 = kpx[1], px2 = kpx[2];
  const float ux0 = kux[0], ux1 = kux[1], ux2 = kux[2];
  const float cx0 = kcx[0], cx1 = kcx[1], cx2 = kcx[2];
  const float rx0 = krx[0], rx1 = krx[1], rx2 = krx[2];

  auto stepm = [&](float (&d)[P], float (&s)[P], float k0, float k1, float k2, float sgn) {
    float L = __shfl_up(s[P - 1], 1); if (lane == 0) L = 0.f;
    float R = __shfl_down(s[0], 1);   if (lane == 63) R = 0.f;
    float prev = L;
#pragma unroll
    for (int j = 0; j < P; j++) {
      float nxt = (j == P - 1) ? R : s[(j + 1) < P ? (j + 1) : 0];
      d[j] += sgn * (k0 * prev + k1 * s[j] + k2 * nxt);
      prev = s[j];
    }
  };

  stepm(o, e, px0, px1, px2, -1.f);
  stepm(e, o, ux0, ux1, ux2,  1.f);
  stepm(o, e, cx0, cx1, cx2, -1.f);
  stepm(e, o, rx0, rx1, rx2,  1.f);

  float* orow = xe_out + ((size_t)img * H + r) * (size_t)W2;
  if (P == 4) {
    *(float4*)(orow + lane * 4) =
        make_float4(e[0], e[P > 1 ? 1 : 0], e[P > 2 ? 2 : 0], e[P > 3 ? 3 : 0]);
  } else {
    *(float2*)(orow + lane * 2) = make_float2(e[0], e[P > 1 ? 1 : 0]);
  }

  float sqd = 0.f;
#pragma unroll
  for (int j = 0; j < P; j++) {
    float d = wrap1(o[j]);
    sqd += d * d;
    if (d >= -1.f && d <= 1.f) atomicAdd(&shd[bin_of(d)], 1u);
  }

  for (int off = 32; off; off >>= 1) {
    sqd += __shfl_down(sqd, off);
    if (do_img) sqi += __shfl_down(sqi, off);
  }
  if (lane == 0) {
    const int bid = blockIdx.x + blockIdx.y * gridDim.x;
    const int slot = (bid * 4 + w) & (NSLOT - 1);
    atomicAdd(&partial[NSLOT + slot], (double)sqd);
    if (do_img) atomicAdd(&partial[slot], (double)sqi);
  }
  __syncthreads();
  unsigned hd = shd[t];
  if (hd) atomicAdd(&hist_delta[img * 256 + t], hd);
  if (do_img) {
    unsigned hi = shi[t];
    if (hi) atomicAdd(&hist_img[img * 256 + t], hi);
  }
}

// ---------------- Kernel B: y-lifting, streaming register pipeline ---------
// Levels 0,1 only (uy always applied). lane = one column. One-row prefetch.
__global__ void __launch_bounds__(64) klift_y_reg(
    const float* __restrict__ xe, float* __restrict__ ye_out,
    const float* __restrict__ kpy, const float* __restrict__ kuy,
    const float* __restrict__ kcy, const float* __restrict__ kry,
    int H2, int W2, int SEG,
    double* __restrict__ partial, unsigned* __restrict__ hist_delta)
{
  __shared__ unsigned shd[256];
  const int lane = threadIdx.x;
  const int img = blockIdx.z;
  const int r0 = blockIdx.y * SEG;
  const int col = blockIdx.x * 64 + lane;
  for (int i = lane; i < 256; i += 64) shd[i] = 0;
  __syncthreads();

  const float py0 = kpy[0], py1 = kpy[1], py2 = kpy[2];
  const float uy0 = kuy[0], uy1 = kuy[1], uy2 = kuy[2];
  const float cy0 = kcy[0], cy1 = kcy[1], cy2 = kcy[2];
  const float ry0 = kry[0], ry1 = kry[1], ry2 = kry[2];

  const float* in = xe + (size_t)img * (2 * H2) * W2 + col;
  float* outp = ye_out + (size_t)img * H2 * W2 + col;

  float eP2 = 0.f, eP1 = 0.f, oP1 = 0.f, aP2 = 0.f, aP1 = 0.f;
  float bP2 = 0.f, bP1 = 0.f, gP2 = 0.f, gP1 = 0.f;

  const int rend = (r0 + SEG < H2) ? r0 + SEG : H2;
  const int rbeg = (r0 >= 4) ? r0 - 4 : 0;
  float sqd = 0.f;

  float eC = in[(size_t)(2 * rbeg) * W2];
  float oC = in[(size_t)(2 * rbeg + 1) * W2];

  for (int r = rbeg; r <= rend + 3; ++r) {
    const int rn = r + 1;
    float eNx = 0.f, oNx = 0.f;
    if (rn < H2 && rn <= rend + 3) {
      eNx = in[(size_t)(2 * rn) * W2];
      oNx = in[(size_t)(2 * rn + 1) * W2];
    }
    const int ia = r - 1, ib = r - 2, ig = r - 3, io = r - 4;
    float aN = (ia >= 0 && ia < H2) ? (oP1 - (py0 * eP2 + py1 * eP1 + py2 * eC)) : 0.f;
    float bN = (ib >= 0 && ib < H2) ? (eP2 + (uy0 * aP2 + uy1 * aP1 + uy2 * aN)) : 0.f;
    float gN = (ig >= 0 && ig < H2) ? (aP2 - (cy0 * bP2 + cy1 * bP1 + cy2 * bN)) : 0.f;
    float fN = (io >= 0 && io < H2) ? (bP2 + (ry0 * gP2 + ry1 * gP1 + ry2 * gN)) : 0.f;
    if (ig >= r0 && ig < rend) {
      float d = wrap1(gN);
      sqd += d * d;
      if (d >= -1.f && d <= 1.f) atomicAdd(&shd[bin_of(d)], 1u);
    }
    if (io >= r0 && io < rend) outp[(size_t)io * W2] = fN;
    eP2 = eP1; eP1 = eC; oP1 = oC;
    aP2 = aP1; aP1 = aN;
    bP2 = bP1; bP1 = bN;
    gP2 = gP1; gP1 = gN;
    eC = eNx; oC = oNx;
  }

  for (int off = 32; off; off >>= 1) sqd += __shfl_down(sqd, off);
  if (lane == 0) {
    const int bid = blockIdx.x + gridDim.x * (blockIdx.y + gridDim.y * blockIdx.z);
    atomicAdd(&partial[NSLOT + (bid & (NSLOT - 1))], (double)sqd);
  }
  __syncthreads();
  for (int i = lane; i < 256; i += 64) {
    unsigned hd = shd[i];
    if (hd) atomicAdd(&hist_delta[img * 256 + i], hd);
  }
}

// ---------------- Kernel C: fused tail, levels 2-4 in LDS, 1 block = 1 image
// src: (NIMG,128,128). In-place strided wavelet. No tensor output (stats only).
// Note: uy is NOT applied at lvl>=2, so the py and cy steps merge: yo -= conv(ye, py+cy).
__global__ void __launch_bounds__(256) klift_tail(
    const float* __restrict__ src,
    const float* __restrict__ kpx, const float* __restrict__ kux,
    const float* __restrict__ kcx, const float* __restrict__ krx,
    const float* __restrict__ kpy, const float* __restrict__ kcy,
    const float* __restrict__ kry,
    double* __restrict__ partial, unsigned* __restrict__ hist_delta)
{
  __shared__ float tile[128][129];
  __shared__ unsigned shd[256];
  const int t = threadIdx.x;
  const int img = blockIdx.x;
  shd[t] = 0;

  const float* sp = src + (size_t)img * 128 * 128;
  for (int idx = t; idx < 128 * 32; idx += 256) {
    const int r = idx >> 5, c4 = (idx & 31) << 2;
    float4 v = *(const float4*)(sp + r * 128 + c4);
    tile[r][c4] = v.x; tile[r][c4 + 1] = v.y;
    tile[r][c4 + 2] = v.z; tile[r][c4 + 3] = v.w;
  }
  const float px0 = kpx[0], px1 = kpx[1], px2 = kpx[2];
  const float ux0 = kux[0], ux1 = kux[1], ux2 = kux[2];
  const float cx0 = kcx[0], cx1 = kcx[1], cx2 = kcx[2];
  const float rx0 = krx[0], rx1 = krx[1], rx2 = krx[2];
  const float pc0 = kpy[0] + kcy[0], pc1 = kpy[1] + kcy[1], pc2 = kpy[2] + kcy[2];
  const float ry0 = kry[0], ry1 = kry[1], ry2 = kry[2];
  float sqd = 0.f;
  __syncthreads();

  for (int l = 0; l < 3; ++l) {
    const int s = 1 << l, n = 128 >> l, half = n >> 1;
    const int totx = n * half;

    // x step 1: xo -= conv(xe, px)
    for (int idx = t; idx < totx; idx += 256) {
      const int r = (idx / half) * s, c = idx % half;
      float L = (c > 0) ? tile[r][(2 * c - 2) * s] : 0.f;
      float M = tile[r][2 * c * s];
      float R = (c < half - 1) ? tile[r][(2 * c + 2) * s] : 0.f;
      tile[r][(2 * c + 1) * s] -= px0 * L + px1 * M + px2 * R;
    }
    __syncthreads();
    // x step 2: xe += conv(xo, ux)
    for (int idx = t; idx < totx; idx += 256) {
      const int r = (idx / half) * s, c = idx % half;
      float L = (c > 0) ? tile[r][(2 * c - 1) * s] : 0.f;
      float M = tile[r][(2 * c + 1) * s];
      float R = (c < half - 1) ? tile[r][(2 * c + 3) * s] : 0.f;
      tile[r][2 * c * s] += ux0 * L + ux1 * M + ux2 * R;
    }
    __syncthreads();
    // x step 3: xo -= conv(xe, cx)
    for (int idx = t; idx < totx; idx += 256) {
      const int r = (idx / half) * s, c = idx % half;
      float L = (c > 0) ? tile[r][(2 * c - 2) * s] : 0.f;
      float M = tile[r][2 * c * s];
      float R = (c < half - 1) ? tile[r][(2 * c + 2) * s] : 0.f;
      tile[r][(2 * c + 1) * s] -= cx0 * L + cx1 * M + cx2 * R;
    }
    __syncthreads();
    // x step 4: xe += conv(xo, rx)
    for (int idx = t; idx < totx; idx += 256) {
      const int r = (idx / half) * s, c = idx % half;
      float L = (c > 0) ? tile[r][(2 * c - 1) * s] : 0.f;
      float M = tile[r][(2 * c + 1) * s];
      float R = (c < half - 1) ? tile[r][(2 * c + 3) * s] : 0.f;
      tile[r][2 * c * s] += rx0 * L + rx1 * M + rx2 * R;
    }
    __syncthreads();
    // xo stats
    for (int idx = t; idx < totx; idx += 256) {
      const int r = (idx / half) * s, c = idx % half;
      float d = wrap1(tile[r][(2 * c + 1) * s]);
      sqd += d * d;
      if (d >= -1.f && d <= 1.f) atomicAdd(&shd[bin_of(d)], 1u);
    }
    // y step 1+3 merged (uy skipped at lvl>=2): yo -= conv(ye, py+cy)
    const int toty = half * half;
    for (int idx = t; idx < toty; idx += 256) {
      const int r = idx / half, j = idx % half, col = j * 2 * s;
      float U = (r > 0) ? tile[(2 * r - 2) * s][col] : 0.f;
      float M = tile[(2 * r) * s][col];
      float D = (r < half - 1) ? tile[(2 * r + 2) * s][col] : 0.f;
      tile[(2 * r + 1) * s][col] -= pc0 * U + pc1 * M + pc2 * D;
    }
    __syncthreads();
    // y step 4: ye += conv(yo, ry)
    for (int idx = t; idx < toty; idx += 256) {
      const int r = idx / half, j = idx % half, col = j * 2 * s;
      float U = (r > 0) ? tile[(2 * r - 1) * s][col] : 0.f;
      float M = tile[(2 * r + 1) * s][col];
      float D = (r < half - 1) ? tile[(2 * r + 3) * s][col] : 0.f;
      tile[(2 * r) * s][col] += ry0 * U + ry1 * M + ry2 * D;
    }
    __syncthreads();
    // yo stats (+ final ye at last level)
    for (int idx = t; idx < toty; idx += 256) {
      const int r = idx / half, j = idx % half, col = j * 2 * s;
      float d = wrap1(tile[(2 * r + 1) * s][col]);
      sqd += d * d;
      if (d >= -1.f && d <= 1.f) atomicAdd(&shd[bin_of(d)], 1u);
      if (l == 2) {
        float d2 = wrap1(tile[(2 * r) * s][col]);
        sqd += d2 * d2;
        if (d2 >= -1.f && d2 <= 1.f) atomicAdd(&shd[bin_of(d2)], 1u);
      }
    }
    __syncthreads();
  }

  // reduce sqd: wave shuffle + cross-wave via LDS
  for (int off = 32; off; off >>= 1) sqd += __shfl_down(sqd, off);
  __shared__ float swv[4];
  if ((t & 63) == 0) swv[t >> 6] = sqd;
  __syncthreads();
  if (t == 0) {
    double tot = (double)swv[0] + swv[1] + swv[2] + swv[3];
    atomicAdd(&partial[NSLOT + (img & (NSLOT - 1))], tot);
  }
  unsigned hd = shd[t];
  if (hd) atomicAdd(&hist_delta[img * 256 + t], hd);
}

// ---------------- Final reduction: entropies + losses -----------------------
__global__ void __launch_bounds__(256) kfinal(
    const double* __restrict__ partial,
    const unsigned* __restrict__ hist_img,
    const unsigned* __restrict__ hist_delta,
    float* __restrict__ out)
{
  __shared__ double sI[256], sD[256], sPi[256], sPd[256];
  const int t = threadIdx.x;
  double entI = 0.0, entD = 0.0;
  for (int img = 0; img < NIMG; ++img) {
    unsigned ci = hist_img[img * 256 + t];
    if (ci) { float p = (float)ci * RES_INV; entI += (double)(-p * log2f(p)); }
    unsigned cd = hist_delta[img * 256 + t];
    if (cd) { float p = (float)cd * RES_INV; entD += (double)(-p * log2f(p)); }
  }
  double pi = 0.0, pd = 0.0;
  for (int s = t; s < NSLOT; s += 256) {
    pi += partial[s];
    pd += partial[NSLOT + s];
  }
  sI[t] = entI; sD[t] = entD; sPi[t] = pi; sPd[t] = pd;
  __syncthreads();
  for (int s = 128; s; s >>= 1) {
    if (t < s) {
      sI[t] += sI[t + s]; sD[t] += sD[t + s];
      sPi[t] += sPi[t + s]; sPd[t] += sPd[t + s];
    }
    __syncthreads();
  }
  if (t == 0) {
    const double tot = (double)NIMG * 262144.0;
    out[0] = (float)(255.0 * sqrt(sPd[0] / tot));  // loss1 (deltas)
    out[1] = (float)(255.0 * sqrt(sPi[0] / tot));  // loss0 (img)
    out[2] = (float)(sI[0] / (8.0 * NIMG));        // invCR0
    out[3] = (float)(sD[0] / (8.0 * NIMG));        // invCR1
  }
}

extern "C" void kernel_launch(void* const* d_in, const int* in_sizes, int n_in,
                              void* d_out, int out_size, void* d_ws, size_t ws_size,
                              hipStream_t stream)
{
  const float* x  = (const float*)d_in[0];
  const float* px = (const float*)d_in[1];
  const float* ux = (const float*)d_in[2];
  const float* cx = (const float*)d_in[3];
  const float* rx = (const float*)d_in[4];
  const float* py = (const float*)d_in[5];
  const float* uy = (const float*)d_in[6];
  const float* cy = (const float*)d_in[7];
  const float* ry = (const float*)d_in[8];
  float* out = (float*)d_out;

  char* ws = (char*)d_ws;
  double*   partial    = (double*)ws;
  unsigned* hist_img   = (unsigned*)(ws + 2 * NSLOT * 8);
  unsigned* hist_delta = (unsigned*)(ws + 2 * NSLOT * 8 + NIMG * 256 * 4);
  float* buf0 = (float*)(ws + (1 << 18));                        // xe
  float* buf1 = (float*)(ws + (1 << 18) + ((size_t)48 << 20));   // ye

  hipMemsetAsync(ws, 0, 2 * NSLOT * 8 + 2 * NIMG * 256 * 4, stream);

  // level 0: 512x512 -> ye (256x256)
  {
    dim3 gA(512 / 4, NIMG);
    klift_x_reg<4><<<gA, 256, 0, stream>>>(x, buf0, px, ux, cx, rx, 512, 256, 1,
                                           partial, hist_img, hist_delta);
    dim3 gB(256 / 64, 256 / 16, NIMG);
    klift_y_reg<<<gB, 64, 0, stream>>>(buf0, buf1, py, uy, cy, ry, 256, 256, 16,
                                       partial, hist_delta);
  }
  // level 1: 256x256 -> ye (128x128)
  {
    dim3 gA(256 / 4, NIMG);
    klift_x_reg<2><<<gA, 256, 0, stream>>>(buf1, buf0, px, ux, cx, rx, 256, 128, 0,
                                           partial, hist_img, hist_delta);
    dim3 gB(128 / 64, 128 / 16, NIMG);
    klift_y_reg<<<gB, 64, 0, stream>>>(buf0, buf1, py, uy, cy, ry, 128, 128, 16,
                                       partial, hist_delta);
  }
  // levels 2-4 fused in LDS (stats only)
  klift_tail<<<NIMG, 256, 0, stream>>>(buf1, px, ux, cx, rx, py, cy, ry,
                                       partial, hist_delta);
  kfinal<<<1, 256, 0, stream>>>(partial, hist_img, hist_delta, out);
}

// Round 5
// 145.940 us; speedup vs baseline: 1.6089x; 1.0149x over previous
//
#include <hip/hip_runtime.h>
#include <math.h>

#define NIMG 96
#define NSLOT 1024
#define RES_INV (1.0f / 262144.0f)   // 1 / (512*512)

// exact fmod(v+1,2)-1 for our range
__device__ __forceinline__ float wrap1(float v) {
  float t = v + 1.0f;
  return t - 2.0f * truncf(t * 0.5f) - 1.0f;
}
__device__ __forceinline__ int bin_of(float v) {
  float b = floorf((v + 1.0f) * 128.0f);
  b = fminf(fmaxf(b, 0.0f), 255.0f);
  return (int)b;
}

// ---------------- Fused per-level kernel: x-lift (reg+shuffle) + y-lift -----
// One block = one image stripe of SEGP interior pair-rows (+4 halo pair-rows
// above/below). src: (NIMG, H, 2*W2); ye_out: (NIMG, H2, W2). W2 = H2 = 64*P.
// x-lifted xe (even stream only) lives in LDS; xo/yo go straight to stats.
template<int P, int SEGP, int CSPLIT, int DO_IMG>
__global__ void __launch_bounds__(256) klift_fused(
    const float* __restrict__ src, float* __restrict__ ye_out,
    const float* __restrict__ kpx, const float* __restrict__ kux,
    const float* __restrict__ kcx, const float* __restrict__ krx,
    const float* __restrict__ kpy, const float* __restrict__ kuy,
    const float* __restrict__ kcy, const float* __restrict__ kry,
    double* __restrict__ partial,
    unsigned* __restrict__ hist_img, unsigned* __restrict__ hist_delta)
{
  constexpr int W2 = 64 * P;          // pairs per row
  constexpr int H2 = W2;              // pair-rows in image
  constexpr int H  = 2 * H2;          // input rows
  constexpr int NR = 2 * SEGP + 16;   // LDS rows (interior + 8 halo each side)
  __shared__ float tile[NR][W2];
  __shared__ unsigned shd[256];
  __shared__ unsigned shi[256];

  const int t = threadIdx.x, w = t >> 6, lane = t & 63;
  const int img = blockIdx.y;
  const int R0 = blockIdx.x * SEGP;
  const int Rend = (R0 + SEGP < H2) ? R0 + SEGP : H2;
  const int base_in = 2 * R0 - 8;     // global input row of LDS row 0

  shd[t] = 0;
  if (DO_IMG) shi[t] = 0;
  __syncthreads();

  const float px0 = kpx[0], px1 = kpx[1], px2 = kpx[2];
  const float ux0 = kux[0], ux1 = kux[1], ux2 = kux[2];
  const float cx0 = kcx[0], cx1 = kcx[1], cx2 = kcx[2];
  const float rx0 = krx[0], rx1 = krx[1], rx2 = krx[2];
  const float py0 = kpy[0], py1 = kpy[1], py2 = kpy[2];
  const float uy0 = kuy[0], uy1 = kuy[1], uy2 = kuy[2];
  const float cy0 = kcy[0], cy1 = kcy[1], cy2 = kcy[2];
  const float ry0 = kry[0], ry1 = kry[1], ry2 = kry[2];

  const float* ip = src + (size_t)img * H * (2 * W2);
  float sqi = 0.f, sqd = 0.f;

  auto stepm = [&](float (&d)[P], float (&s)[P], float k0, float k1, float k2, float sgn) {
    float L = __shfl_up(s[P - 1], 1); if (lane == 0) L = 0.f;
    float R = __shfl_down(s[0], 1);   if (lane == 63) R = 0.f;
    float prev = L;
#pragma unroll
    for (int j = 0; j < P; j++) {
      float nxt = (j == P - 1) ? R : s[(j + 1) < P ? (j + 1) : 0];
      d[j] += sgn * (k0 * prev + k1 * s[j] + k2 * nxt);
      prev = s[j];
    }
  };
  auto ldrow = [&](int lr, float4& A, float4& B) {
    const int gin = base_in + lr;
    if (gin >= 0 && gin < H) {
      const float* rp = ip + (size_t)gin * (2 * W2) + lane * (2 * P);
      A = *(const float4*)rp;
      if (P == 4) B = *(const float4*)(rp + 4);
    } else {
      A = make_float4(0.f, 0.f, 0.f, 0.f);
      B = make_float4(0.f, 0.f, 0.f, 0.f);
    }
  };

  // ---- x phase: wave w handles LDS rows w, w+4, ... (one full row each) ----
  float4 cA, cB, nA, nB;
  ldrow(w, cA, cB);
  for (int lr = w; lr < NR; lr += 4) {
    if (lr + 4 < NR) ldrow(lr + 4, nA, nB);
    const int gin = base_in + lr;
    const bool owned = (gin >= 2 * R0) && (gin < 2 * Rend);
    float e[P], o[P];
    e[0] = cA.x; o[0] = cA.y;
    if (P >= 2) { e[P > 1 ? 1 : 0] = cA.z; o[P > 1 ? 1 : 0] = cA.w; }
    if (P == 4) {
      e[P > 2 ? 2 : 0] = cB.x; o[P > 2 ? 2 : 0] = cB.y;
      e[P > 3 ? 3 : 0] = cB.z; o[P > 3 ? 3 : 0] = cB.w;
    }
    if (DO_IMG && owned) {
#pragma unroll
      for (int j = 0; j < P; j++) {
        sqi += e[j] * e[j] + o[j] * o[j];
        atomicAdd(&shi[bin_of(e[j])], 1u);
        atomicAdd(&shi[bin_of(o[j])], 1u);
      }
    }
    stepm(o, e, px0, px1, px2, -1.f);
    stepm(e, o, ux0, ux1, ux2,  1.f);
    stepm(o, e, cx0, cx1, cx2, -1.f);
    stepm(e, o, rx0, rx1, rx2,  1.f);
    if (P == 4) {
      *(float4*)&tile[lr][lane * 4] =
          make_float4(e[0], e[P > 1 ? 1 : 0], e[P > 2 ? 2 : 0], e[P > 3 ? 3 : 0]);
    } else {
      *(float2*)&tile[lr][lane * 2] = make_float2(e[0], e[P > 1 ? 1 : 0]);
    }
    if (owned) {
#pragma unroll
      for (int j = 0; j < P; j++) {
        float d = wrap1(o[j]);
        sqd += d * d;
        if (d >= -1.f && d <= 1.f) atomicAdd(&shd[bin_of(d)], 1u);
      }
    }
    cA = nA; cB = nB;
  }
  __syncthreads();

  // ---- y phase: thread = one column (CSPLIT row-subsegments per column) ----
  {
    const int col = t % W2;
    const int half = t / W2;
    const int lenI = Rend - R0;
    const int s1 = (lenI + CSPLIT - 1) / CSPLIT;
    const int r0s = R0 + half * s1;
    const int rends = (r0s + s1 < Rend) ? r0s + s1 : Rend;

    float eP2 = 0.f, eP1 = 0.f, oP1 = 0.f, aP2 = 0.f, aP1 = 0.f;
    float bP2 = 0.f, bP1 = 0.f, gP2 = 0.f, gP1 = 0.f;
    float* outp = ye_out + (size_t)img * H2 * W2 + col;

    for (int r = r0s - 4; r <= rends + 3; ++r) {
      const int lrE = 2 * (r - R0) + 8;
      const float eC = tile[lrE][col];
      const float oC = tile[lrE + 1][col];
      const int ia = r - 1, ib = r - 2, ig = r - 3, io = r - 4;
      float aN = (ia >= 0 && ia < H2) ? (oP1 - (py0 * eP2 + py1 * eP1 + py2 * eC)) : 0.f;
      float bN = (ib >= 0 && ib < H2) ? (eP2 + (uy0 * aP2 + uy1 * aP1 + uy2 * aN)) : 0.f;
      float gN = (ig >= 0 && ig < H2) ? (aP2 - (cy0 * bP2 + cy1 * bP1 + cy2 * bN)) : 0.f;
      float fN = (io >= 0 && io < H2) ? (bP2 + (ry0 * gP2 + ry1 * gP1 + ry2 * gN)) : 0.f;
      if (ig >= r0s && ig < rends) {
        float d = wrap1(gN);
        sqd += d * d;
        if (d >= -1.f && d <= 1.f) atomicAdd(&shd[bin_of(d)], 1u);
      }
      if (io >= r0s && io < rends) outp[(size_t)io * W2] = fN;
      eP2 = eP1; eP1 = eC; oP1 = oC;
      aP2 = aP1; aP1 = aN;
      bP2 = bP1; bP1 = bN;
      gP2 = gP1; gP1 = gN;
    }
  }

  // ---- reduce + flush ----
  for (int off = 32; off; off >>= 1) {
    sqd += __shfl_down(sqd, off);
    if (DO_IMG) sqi += __shfl_down(sqi, off);
  }
  if (lane == 0) {
    const int bid = blockIdx.x + blockIdx.y * gridDim.x;
    const int slot = (bid * 4 + w) & (NSLOT - 1);
    atomicAdd(&partial[NSLOT + slot], (double)sqd);
    if (DO_IMG) atomicAdd(&partial[slot], (double)sqi);
  }
  __syncthreads();
  unsigned hd = shd[t];
  if (hd) atomicAdd(&hist_delta[img * 256 + t], hd);
  if (DO_IMG) {
    unsigned hi = shi[t];
    if (hi) atomicAdd(&hist_img[img * 256 + t], hi);
  }
}

// ---------------- Kernel C: fused tail, levels 2-4 in LDS, 1 block = 1 image
// src: (NIMG,128,128). In-place strided wavelet. Stats only.
// uy is NOT applied at lvl>=2, so py and cy steps merge: yo -= conv(ye, py+cy).
__global__ void __launch_bounds__(256) klift_tail(
    const float* __restrict__ src,
    const float* __restrict__ kpx, const float* __restrict__ kux,
    const float* __restrict__ kcx, const float* __restrict__ krx,
    const float* __restrict__ kpy, const float* __restrict__ kcy,
    const float* __restrict__ kry,
    double* __restrict__ partial, unsigned* __restrict__ hist_delta)
{
  __shared__ float tile[128][129];
  __shared__ unsigned shd[256];
  const int t = threadIdx.x;
  const int img = blockIdx.x;
  shd[t] = 0;

  const float* sp = src + (size_t)img * 128 * 128;
  for (int idx = t; idx < 128 * 32; idx += 256) {
    const int r = idx >> 5, c4 = (idx & 31) << 2;
    float4 v = *(const float4*)(sp + r * 128 + c4);
    tile[r][c4] = v.x; tile[r][c4 + 1] = v.y;
    tile[r][c4 + 2] = v.z; tile[r][c4 + 3] = v.w;
  }
  const float px0 = kpx[0], px1 = kpx[1], px2 = kpx[2];
  const float ux0 = kux[0], ux1 = kux[1], ux2 = kux[2];
  const float cx0 = kcx[0], cx1 = kcx[1], cx2 = kcx[2];
  const float rx0 = krx[0], rx1 = krx[1], rx2 = krx[2];
  const float pc0 = kpy[0] + kcy[0], pc1 = kpy[1] + kcy[1], pc2 = kpy[2] + kcy[2];
  const float ry0 = kry[0], ry1 = kry[1], ry2 = kry[2];
  float sqd = 0.f;
  __syncthreads();

  for (int l = 0; l < 3; ++l) {
    const int s = 1 << l, n = 128 >> l, half = n >> 1;
    const int totx = n * half;

    for (int idx = t; idx < totx; idx += 256) {
      const int r = (idx / half) * s, c = idx % half;
      float L = (c > 0) ? tile[r][(2 * c - 2) * s] : 0.f;
      float M = tile[r][2 * c * s];
      float R = (c < half - 1) ? tile[r][(2 * c + 2) * s] : 0.f;
      tile[r][(2 * c + 1) * s] -= px0 * L + px1 * M + px2 * R;
    }
    __syncthreads();
    for (int idx = t; idx < totx; idx += 256) {
      const int r = (idx / half) * s, c = idx % half;
      float L = (c > 0) ? tile[r][(2 * c - 1) * s] : 0.f;
      float M = tile[r][(2 * c + 1) * s];
      float R = (c < half - 1) ? tile[r][(2 * c + 3) * s] : 0.f;
      tile[r][2 * c * s] += ux0 * L + ux1 * M + ux2 * R;
    }
    __syncthreads();
    for (int idx = t; idx < totx; idx += 256) {
      const int r = (idx / half) * s, c = idx % half;
      float L = (c > 0) ? tile[r][(2 * c - 2) * s] : 0.f;
      float M = tile[r][2 * c * s];
      float R = (c < half - 1) ? tile[r][(2 * c + 2) * s] : 0.f;
      tile[r][(2 * c + 1) * s] -= cx0 * L + cx1 * M + cx2 * R;
    }
    __syncthreads();
    for (int idx = t; idx < totx; idx += 256) {
      const int r = (idx / half) * s, c = idx % half;
      float L = (c > 0) ? tile[r][(2 * c - 1) * s] : 0.f;
      float M = tile[r][(2 * c + 1) * s];
      float R = (c < half - 1) ? tile[r][(2 * c + 3) * s] : 0.f;
      tile[r][2 * c * s] += rx0 * L + rx1 * M + rx2 * R;
    }
    __syncthreads();
    for (int idx = t; idx < totx; idx += 256) {
      const int r = (idx / half) * s, c = idx % half;
      float d = wrap1(tile[r][(2 * c + 1) * s]);
      sqd += d * d;
      if (d >= -1.f && d <= 1.f) atomicAdd(&shd[bin_of(d)], 1u);
    }
    const int toty = half * half;
    for (int idx = t; idx < toty; idx += 256) {
      const int r = idx / half, j = idx % half, col = j * 2 * s;
      float U = (r > 0) ? tile[(2 * r - 2) * s][col] : 0.f;
      float M = tile[(2 * r) * s][col];
      float D = (r < half - 1) ? tile[(2 * r + 2) * s][col] : 0.f;
      tile[(2 * r + 1) * s][col] -= pc0 * U + pc1 * M + pc2 * D;
    }
    __syncthreads();
    for (int idx = t; idx < toty; idx += 256) {
      const int r = idx / half, j = idx % half, col = j * 2 * s;
      float U = (r > 0) ? tile[(2 * r - 1) * s][col] : 0.f;
      float M = tile[(2 * r + 1) * s][col];
      float D = (r < half - 1) ? tile[(2 * r + 3) * s][col] : 0.f;
      tile[(2 * r) * s][col] += ry0 * U + ry1 * M + ry2 * D;
    }
    __syncthreads();
    for (int idx = t; idx < toty; idx += 256) {
      const int r = idx / half, j = idx % half, col = j * 2 * s;
      float d = wrap1(tile[(2 * r + 1) * s][col]);
      sqd += d * d;
      if (d >= -1.f && d <= 1.f) atomicAdd(&shd[bin_of(d)], 1u);
      if (l == 2) {
        float d2 = wrap1(tile[(2 * r) * s][col]);
        sqd += d2 * d2;
        if (d2 >= -1.f && d2 <= 1.f) atomicAdd(&shd[bin_of(d2)], 1u);
      }
    }
    __syncthreads();
  }

  for (int off = 32; off; off >>= 1) sqd += __shfl_down(sqd, off);
  __shared__ float swv[4];
  if ((t & 63) == 0) swv[t >> 6] = sqd;
  __syncthreads();
  if (t == 0) {
    double tot = (double)swv[0] + swv[1] + swv[2] + swv[3];
    atomicAdd(&partial[NSLOT + (img & (NSLOT - 1))], tot);
  }
  unsigned hd = shd[t];
  if (hd) atomicAdd(&hist_delta[img * 256 + t], hd);
}

// ---------------- Final reduction: entropies + losses -----------------------
__global__ void __launch_bounds__(256) kfinal(
    const double* __restrict__ partial,
    const unsigned* __restrict__ hist_img,
    const unsigned* __restrict__ hist_delta,
    float* __restrict__ out)
{
  __shared__ double sI[256], sD[256], sPi[256], sPd[256];
  const int t = threadIdx.x;
  double entI = 0.0, entD = 0.0;
  for (int img = 0; img < NIMG; ++img) {
    unsigned ci = hist_img[img * 256 + t];
    if (ci) { float p = (float)ci * RES_INV; entI += (double)(-p * log2f(p)); }
    unsigned cd = hist_delta[img * 256 + t];
    if (cd) { float p = (float)cd * RES_INV; entD += (double)(-p * log2f(p)); }
  }
  double pi = 0.0, pd = 0.0;
  for (int s = t; s < NSLOT; s += 256) {
    pi += partial[s];
    pd += partial[NSLOT + s];
  }
  sI[t] = entI; sD[t] = entD; sPi[t] = pi; sPd[t] = pd;
  __syncthreads();
  for (int s = 128; s; s >>= 1) {
    if (t < s) {
      sI[t] += sI[t + s]; sD[t] += sD[t + s];
      sPi[t] += sPi[t + s]; sPd[t] += sPd[t + s];
    }
    __syncthreads();
  }
  if (t == 0) {
    const double tot = (double)NIMG * 262144.0;
    out[0] = (float)(255.0 * sqrt(sPd[0] / tot));  // loss1 (deltas)
    out[1] = (float)(255.0 * sqrt(sPi[0] / tot));  // loss0 (img)
    out[2] = (float)(sI[0] / (8.0 * NIMG));        // invCR0
    out[3] = (float)(sD[0] / (8.0 * NIMG));        // invCR1
  }
}

extern "C" void kernel_launch(void* const* d_in, const int* in_sizes, int n_in,
                              void* d_out, int out_size, void* d_ws, size_t ws_size,
                              hipStream_t stream)
{
  const float* x  = (const float*)d_in[0];
  const float* px = (const float*)d_in[1];
  const float* ux = (const float*)d_in[2];
  const float* cx = (const float*)d_in[3];
  const float* rx = (const float*)d_in[4];
  const float* py = (const float*)d_in[5];
  const float* uy = (const float*)d_in[6];
  const float* cy = (const float*)d_in[7];
  const float* ry = (const float*)d_in[8];
  float* out = (float*)d_out;

  char* ws = (char*)d_ws;
  double*   partial    = (double*)ws;
  unsigned* hist_img   = (unsigned*)(ws + 2 * NSLOT * 8);
  unsigned* hist_delta = (unsigned*)(ws + 2 * NSLOT * 8 + NIMG * 256 * 4);
  float* buf0 = (float*)(ws + (1 << 18));                        // ye0: 256x256x96 = 25.2MB
  float* buf1 = (float*)(ws + (1 << 18) + ((size_t)32 << 20));   // ye1: 128x128x96 = 6.3MB

  hipMemsetAsync(ws, 0, 2 * NSLOT * 8 + 2 * NIMG * 256 * 4, stream);

  // level 0: 512x512 -> ye0 (256x256), img+delta stats. 11 tiles of 24 pair-rows.
  klift_fused<4, 24, 1, 1><<<dim3(11, NIMG), 256, 0, stream>>>(
      x, buf0, px, ux, cx, rx, py, uy, cy, ry, partial, hist_img, hist_delta);
  // level 1: 256x256 -> ye1 (128x128). 6 tiles, 2 column-subsegments.
  klift_fused<2, 24, 2, 0><<<dim3(6, NIMG), 256, 0, stream>>>(
      buf0, buf1, px, ux, cx, rx, py, uy, cy, ry, partial, hist_img, hist_delta);
  // levels 2-4 fused in LDS (stats only)
  klift_tail<<<NIMG, 256, 0, stream>>>(buf1, px, ux, cx, rx, py, cy, ry,
                                       partial, hist_delta);
  kfinal<<<1, 256, 0, stream>>>(partial, hist_img, hist_delta, out);
}

// Round 6
// 136.422 us; speedup vs baseline: 1.7211x; 1.0698x over previous
//
#include <hip/hip_runtime.h>
#include <math.h>

#define NIMG 96
#define NSLOT 1024
#define RES_INV (1.0f / 262144.0f)   // 1 / (512*512)

// exact fmod(v+1,2)-1 for our range
__device__ __forceinline__ float wrap1(float v) {
  float t = v + 1.0f;
  return t - 2.0f * truncf(t * 0.5f) - 1.0f;
}
__device__ __forceinline__ int bin_of(float v) {
  float b = floorf((v + 1.0f) * 128.0f);
  b = fminf(fmaxf(b, 0.0f), 255.0f);
  return (int)b;
}

// ---------------- Fused per-level kernel ------------------------------------
// x-lift in registers+shuffles (wave per row), xe -> LDS (interleaved rows);
// y-lift as 4 PARALLEL in-LDS conv steps (validity shrinks 1 pair-row/side
// per step; 4-pair-row halos each side make the interior exact; outside-image
// rows are zeros and stay zeros = reference zero-pad).
// src: (NIMG, H, 2*W2); ye_out: (NIMG, H2, W2). W2 = H2 = 64*P.
template<int P, int SEGP, int USE_UY, int DO_IMG>
__global__ void __launch_bounds__(256) klift_fused(
    const float* __restrict__ src, float* __restrict__ ye_out,
    const float* __restrict__ kpx, const float* __restrict__ kux,
    const float* __restrict__ kcx, const float* __restrict__ krx,
    const float* __restrict__ kpy, const float* __restrict__ kuy,
    const float* __restrict__ kcy, const float* __restrict__ kry,
    double* __restrict__ partial,
    unsigned* __restrict__ hist_img, unsigned* __restrict__ hist_delta)
{
  constexpr int W2 = 64 * P;          // pairs per row = out width
  constexpr int H2 = W2;              // pair-rows in image (square levels)
  constexpr int H  = 2 * H2;          // input rows
  constexpr int NP = SEGP + 8;        // LDS pair-rows (4 halo each side)
  constexpr int NR = 2 * NP;          // LDS input rows
  __shared__ float tile[NR][W2];
  __shared__ unsigned shd[256];
  __shared__ unsigned shi[256];

  const int t = threadIdx.x, w = t >> 6, lane = t & 63;
  const int img = blockIdx.y;
  const int R0 = blockIdx.x * SEGP;        // first interior pair-row
  const int Rend = (R0 + SEGP < H2) ? R0 + SEGP : H2;
  const int base_in = 2 * R0 - 8;          // input row of LDS row 0

  shd[t] = 0;
  if (DO_IMG) shi[t] = 0;
  __syncthreads();

  const float px0 = kpx[0], px1 = kpx[1], px2 = kpx[2];
  const float ux0 = kux[0], ux1 = kux[1], ux2 = kux[2];
  const float cx0 = kcx[0], cx1 = kcx[1], cx2 = kcx[2];
  const float rx0 = krx[0], rx1 = krx[1], rx2 = krx[2];
  const float py0 = kpy[0], py1 = kpy[1], py2 = kpy[2];
  const float uy0 = kuy[0], uy1 = kuy[1], uy2 = kuy[2];
  const float cy0 = kcy[0], cy1 = kcy[1], cy2 = kcy[2];
  const float ry0 = kry[0], ry1 = kry[1], ry2 = kry[2];

  const float* ip = src + (size_t)img * H * (2 * W2);
  float sqi = 0.f, sqd = 0.f;

  auto stepm = [&](float (&d)[P], float (&s)[P], float k0, float k1, float k2, float sgn) {
    float L = __shfl_up(s[P - 1], 1); if (lane == 0) L = 0.f;
    float R = __shfl_down(s[0], 1);   if (lane == 63) R = 0.f;
    float prev = L;
#pragma unroll
    for (int j = 0; j < P; j++) {
      float nxt = (j == P - 1) ? R : s[(j + 1) < P ? (j + 1) : 0];
      d[j] += sgn * (k0 * prev + k1 * s[j] + k2 * nxt);
      prev = s[j];
    }
  };
  auto ldrow = [&](int lr, float4& A, float4& B) {
    const int gin = base_in + lr;
    if (gin >= 0 && gin < H) {
      const float* rp = ip + (size_t)gin * (2 * W2) + lane * (2 * P);
      A = *(const float4*)rp;
      if (P == 4) B = *(const float4*)(rp + 4);
    } else {
      A = make_float4(0.f, 0.f, 0.f, 0.f);
      B = make_float4(0.f, 0.f, 0.f, 0.f);
    }
  };

  // ---- x phase: wave w handles LDS rows w, w+4, ... (one full row each) ----
  float4 cA, cB, nA, nB;
  ldrow(w, cA, cB);
  for (int lr = w; lr < NR; lr += 4) {
    if (lr + 4 < NR) ldrow(lr + 4, nA, nB);
    const int gin = base_in + lr;
    const bool owned = (gin >= 2 * R0) && (gin < 2 * Rend);
    float e[P], o[P];
    e[0] = cA.x; o[0] = cA.y;
    if (P >= 2) { e[P > 1 ? 1 : 0] = cA.z; o[P > 1 ? 1 : 0] = cA.w; }
    if (P == 4) {
      e[P > 2 ? 2 : 0] = cB.x; o[P > 2 ? 2 : 0] = cB.y;
      e[P > 3 ? 3 : 0] = cB.z; o[P > 3 ? 3 : 0] = cB.w;
    }
    if (DO_IMG && owned) {
#pragma unroll
      for (int j = 0; j < P; j++) {
        sqi += e[j] * e[j] + o[j] * o[j];
        atomicAdd(&shi[bin_of(e[j])], 1u);
        atomicAdd(&shi[bin_of(o[j])], 1u);
      }
    }
    stepm(o, e, px0, px1, px2, -1.f);
    stepm(e, o, ux0, ux1, ux2,  1.f);
    stepm(o, e, cx0, cx1, cx2, -1.f);
    stepm(e, o, rx0, rx1, rx2,  1.f);
    if (P == 4) {
      *(float4*)&tile[lr][lane * 4] =
          make_float4(e[0], e[P > 1 ? 1 : 0], e[P > 2 ? 2 : 0], e[P > 3 ? 3 : 0]);
    } else {
      *(float2*)&tile[lr][lane * 2] = make_float2(e[0], e[P > 1 ? 1 : 0]);
    }
    if (owned) {
#pragma unroll
      for (int j = 0; j < P; j++) {
        float d = wrap1(o[j]);
        sqd += d * d;
        if (d >= -1.f && d <= 1.f) atomicAdd(&shd[bin_of(d)], 1u);
      }
    }
    cA = nA; cB = nB;
  }
  __syncthreads();

  // ---- y phase: 4 parallel lifting steps over pair-rows --------------------
  // stream views: ye_s[q] = tile[2q][col], yo_s[q] = tile[2q+1][col]
  {
    constexpr int TOT = NP * W2;
    // step 1: yo -= conv(ye, py)
    for (int idx = t; idx < TOT; idx += 256) {
      const int q = idx / W2, col = idx % W2;
      float U = (q > 0) ? tile[2 * q - 2][col] : 0.f;
      float M = tile[2 * q][col];
      float D = (q < NP - 1) ? tile[2 * q + 2][col] : 0.f;
      tile[2 * q + 1][col] -= py0 * U + py1 * M + py2 * D;
    }
    __syncthreads();
    // step 2: ye += conv(yo, uy)   (levels 0,1 only)
    if (USE_UY) {
      for (int idx = t; idx < TOT; idx += 256) {
        const int q = idx / W2, col = idx % W2;
        float U = (q > 0) ? tile[2 * q - 1][col] : 0.f;
        float M = tile[2 * q + 1][col];
        float D = (q < NP - 1) ? tile[2 * q + 3][col] : 0.f;
        tile[2 * q][col] += uy0 * U + uy1 * M + uy2 * D;
      }
      __syncthreads();
    }
    // step 3: yo -= conv(ye, cy)
    for (int idx = t; idx < TOT; idx += 256) {
      const int q = idx / W2, col = idx % W2;
      float U = (q > 0) ? tile[2 * q - 2][col] : 0.f;
      float M = tile[2 * q][col];
      float D = (q < NP - 1) ? tile[2 * q + 2][col] : 0.f;
      tile[2 * q + 1][col] -= cy0 * U + cy1 * M + cy2 * D;
    }
    __syncthreads();
    // step 4: ye += conv(yo, ry)
    for (int idx = t; idx < TOT; idx += 256) {
      const int q = idx / W2, col = idx % W2;
      float U = (q > 0) ? tile[2 * q - 1][col] : 0.f;
      float M = tile[2 * q + 1][col];
      float D = (q < NP - 1) ? tile[2 * q + 3][col] : 0.f;
      tile[2 * q][col] += ry0 * U + ry1 * M + ry2 * D;
    }
    __syncthreads();
    // stats (yo) + store (ye), interior pair-rows only
    const int lenI = Rend - R0;
    float* outp = ye_out + ((size_t)img * H2 + R0) * W2;
    for (int idx = t; idx < lenI * W2; idx += 256) {
      const int qr = idx / W2, col = idx % W2;
      const int q = qr + 4;
      float yov = tile[2 * q + 1][col];
      float d = wrap1(yov);
      sqd += d * d;
      if (d >= -1.f && d <= 1.f) atomicAdd(&shd[bin_of(d)], 1u);
      outp[(size_t)qr * W2 + col] = tile[2 * q][col];
    }
  }

  // ---- reduce + flush ----
  for (int off = 32; off; off >>= 1) {
    sqd += __shfl_down(sqd, off);
    if (DO_IMG) sqi += __shfl_down(sqi, off);
  }
  if (lane == 0) {
    const int bid = blockIdx.x + blockIdx.y * gridDim.x;
    const int slot = (bid * 4 + w) & (NSLOT - 1);
    atomicAdd(&partial[NSLOT + slot], (double)sqd);
    if (DO_IMG) atomicAdd(&partial[slot], (double)sqi);
  }
  __syncthreads();
  unsigned hd = shd[t];
  if (hd) atomicAdd(&hist_delta[img * 256 + t], hd);
  if (DO_IMG) {
    unsigned hi = shi[t];
    if (hi) atomicAdd(&hist_img[img * 256 + t], hi);
  }
}

// ---------------- Kernel C: fused tail, levels 2-4 in LDS, 1 block = 1 image
// src: (NIMG,128,128). In-place strided wavelet. Stats only.
// uy is NOT applied at lvl>=2, so py and cy steps merge: yo -= conv(ye, py+cy).
__global__ void __launch_bounds__(256) klift_tail(
    const float* __restrict__ src,
    const float* __restrict__ kpx, const float* __restrict__ kux,
    const float* __restrict__ kcx, const float* __restrict__ krx,
    const float* __restrict__ kpy, const float* __restrict__ kcy,
    const float* __restrict__ kry,
    double* __restrict__ partial, unsigned* __restrict__ hist_delta)
{
  __shared__ float tile[128][129];
  __shared__ unsigned shd[256];
  const int t = threadIdx.x;
  const int img = blockIdx.x;
  shd[t] = 0;

  const float* sp = src + (size_t)img * 128 * 128;
  for (int idx = t; idx < 128 * 32; idx += 256) {
    const int r = idx >> 5, c4 = (idx & 31) << 2;
    float4 v = *(const float4*)(sp + r * 128 + c4);
    tile[r][c4] = v.x; tile[r][c4 + 1] = v.y;
    tile[r][c4 + 2] = v.z; tile[r][c4 + 3] = v.w;
  }
  const float px0 = kpx[0], px1 = kpx[1], px2 = kpx[2];
  const float ux0 = kux[0], ux1 = kux[1], ux2 = kux[2];
  const float cx0 = kcx[0], cx1 = kcx[1], cx2 = kcx[2];
  const float rx0 = krx[0], rx1 = krx[1], rx2 = krx[2];
  const float pc0 = kpy[0] + kcy[0], pc1 = kpy[1] + kcy[1], pc2 = kpy[2] + kcy[2];
  const float ry0 = kry[0], ry1 = kry[1], ry2 = kry[2];
  float sqd = 0.f;
  __syncthreads();

  for (int l = 0; l < 3; ++l) {
    const int s = 1 << l, n = 128 >> l, half = n >> 1;
    const int totx = n * half;

    for (int idx = t; idx < totx; idx += 256) {
      const int r = (idx / half) * s, c = idx % half;
      float L = (c > 0) ? tile[r][(2 * c - 2) * s] : 0.f;
      float M = tile[r][2 * c * s];
      float R = (c < half - 1) ? tile[r][(2 * c + 2) * s] : 0.f;
      tile[r][(2 * c + 1) * s] -= px0 * L + px1 * M + px2 * R;
    }
    __syncthreads();
    for (int idx = t; idx < totx; idx += 256) {
      const int r = (idx / half) * s, c = idx % half;
      float L = (c > 0) ? tile[r][(2 * c - 1) * s] : 0.f;
      float M = tile[r][(2 * c + 1) * s];
      float R = (c < half - 1) ? tile[r][(2 * c + 3) * s] : 0.f;
      tile[r][2 * c * s] += ux0 * L + ux1 * M + ux2 * R;
    }
    __syncthreads();
    for (int idx = t; idx < totx; idx += 256) {
      const int r = (idx / half) * s, c = idx % half;
      float L = (c > 0) ? tile[r][(2 * c - 2) * s] : 0.f;
      float M = tile[r][2 * c * s];
      float R = (c < half - 1) ? tile[r][(2 * c + 2) * s] : 0.f;
      tile[r][(2 * c + 1) * s] -= cx0 * L + cx1 * M + cx2 * R;
    }
    __syncthreads();
    for (int idx = t; idx < totx; idx += 256) {
      const int r = (idx / half) * s, c = idx % half;
      float L = (c > 0) ? tile[r][(2 * c - 1) * s] : 0.f;
      float M = tile[r][(2 * c + 1) * s];
      float R = (c < half - 1) ? tile[r][(2 * c + 3) * s] : 0.f;
      tile[r][2 * c * s] += rx0 * L + rx1 * M + rx2 * R;
    }
    __syncthreads();
    for (int idx = t; idx < totx; idx += 256) {
      const int r = (idx / half) * s, c = idx % half;
      float d = wrap1(tile[r][(2 * c + 1) * s]);
      sqd += d * d;
      if (d >= -1.f && d <= 1.f) atomicAdd(&shd[bin_of(d)], 1u);
    }
    const int toty = half * half;
    for (int idx = t; idx < toty; idx += 256) {
      const int r = idx / half, j = idx % half, col = j * 2 * s;
      float U = (r > 0) ? tile[(2 * r - 2) * s][col] : 0.f;
      float M = tile[(2 * r) * s][col];
      float D = (r < half - 1) ? tile[(2 * r + 2) * s][col] : 0.f;
      tile[(2 * r + 1) * s][col] -= pc0 * U + pc1 * M + pc2 * D;
    }
    __syncthreads();
    for (int idx = t; idx < toty; idx += 256) {
      const int r = idx / half, j = idx % half, col = j * 2 * s;
      float U = (r > 0) ? tile[(2 * r - 1) * s][col] : 0.f;
      float M = tile[(2 * r + 1) * s][col];
      float D = (r < half - 1) ? tile[(2 * r + 3) * s][col] : 0.f;
      tile[(2 * r) * s][col] += ry0 * U + ry1 * M + ry2 * D;
    }
    __syncthreads();
    for (int idx = t; idx < toty; idx += 256) {
      const int r = idx / half, j = idx % half, col = j * 2 * s;
      float d = wrap1(tile[(2 * r + 1) * s][col]);
      sqd += d * d;
      if (d >= -1.f && d <= 1.f) atomicAdd(&shd[bin_of(d)], 1u);
      if (l == 2) {
        float d2 = wrap1(tile[(2 * r) * s][col]);
        sqd += d2 * d2;
        if (d2 >= -1.f && d2 <= 1.f) atomicAdd(&shd[bin_of(d2)], 1u);
      }
    }
    __syncthreads();
  }

  for (int off = 32; off; off >>= 1) sqd += __shfl_down(sqd, off);
  __shared__ float swv[4];
  if ((t & 63) == 0) swv[t >> 6] = sqd;
  __syncthreads();
  if (t == 0) {
    double tot = (double)swv[0] + swv[1] + swv[2] + swv[3];
    atomicAdd(&partial[NSLOT + (img & (NSLOT - 1))], tot);
  }
  unsigned hd = shd[t];
  if (hd) atomicAdd(&hist_delta[img * 256 + t], hd);
}

// ---------------- Final reduction: entropies + losses -----------------------
__global__ void __launch_bounds__(256) kfinal(
    const double* __restrict__ partial,
    const unsigned* __restrict__ hist_img,
    const unsigned* __restrict__ hist_delta,
    float* __restrict__ out)
{
  __shared__ double sI[256], sD[256], sPi[256], sPd[256];
  const int t = threadIdx.x;
  double entI = 0.0, entD = 0.0;
  for (int img = 0; img < NIMG; ++img) {
    unsigned ci = hist_img[img * 256 + t];
    if (ci) { float p = (float)ci * RES_INV; entI += (double)(-p * log2f(p)); }
    unsigned cd = hist_delta[img * 256 + t];
    if (cd) { float p = (float)cd * RES_INV; entD += (double)(-p * log2f(p)); }
  }
  double pi = 0.0, pd = 0.0;
  for (int s = t; s < NSLOT; s += 256) {
    pi += partial[s];
    pd += partial[NSLOT + s];
  }
  sI[t] = entI; sD[t] = entD; sPi[t] = pi; sPd[t] = pd;
  __syncthreads();
  for (int s = 128; s; s >>= 1) {
    if (t < s) {
      sI[t] += sI[t + s]; sD[t] += sD[t + s];
      sPi[t] += sPi[t + s]; sPd[t] += sPd[t + s];
    }
    __syncthreads();
  }
  if (t == 0) {
    const double tot = (double)NIMG * 262144.0;
    out[0] = (float)(255.0 * sqrt(sPd[0] / tot));  // loss1 (deltas)
    out[1] = (float)(255.0 * sqrt(sPi[0] / tot));  // loss0 (img)
    out[2] = (float)(sI[0] / (8.0 * NIMG));        // invCR0
    out[3] = (float)(sD[0] / (8.0 * NIMG));        // invCR1
  }
}

extern "C" void kernel_launch(void* const* d_in, const int* in_sizes, int n_in,
                              void* d_out, int out_size, void* d_ws, size_t ws_size,
                              hipStream_t stream)
{
  const float* x  = (const float*)d_in[0];
  const float* px = (const float*)d_in[1];
  const float* ux = (const float*)d_in[2];
  const float* cx = (const float*)d_in[3];
  const float* rx = (const float*)d_in[4];
  const float* py = (const float*)d_in[5];
  const float* uy = (const float*)d_in[6];
  const float* cy = (const float*)d_in[7];
  const float* ry = (const float*)d_in[8];
  float* out = (float*)d_out;

  char* ws = (char*)d_ws;
  double*   partial    = (double*)ws;
  unsigned* hist_img   = (unsigned*)(ws + 2 * NSLOT * 8);
  unsigned* hist_delta = (unsigned*)(ws + 2 * NSLOT * 8 + NIMG * 256 * 4);
  float* buf0 = (float*)(ws + (1 << 18));                        // ye0: 25.2MB
  float* buf1 = (float*)(ws + (1 << 18) + ((size_t)32 << 20));   // ye1: 6.3MB

  hipMemsetAsync(ws, 0, 2 * NSLOT * 8 + 2 * NIMG * 256 * 4, stream);

  // level 0: 512x512 -> ye0 (256x256), img+delta stats. 16 stripes of 16 pair-rows.
  klift_fused<4, 16, 1, 1><<<dim3(16, NIMG), 256, 0, stream>>>(
      x, buf0, px, ux, cx, rx, py, uy, cy, ry, partial, hist_img, hist_delta);
  // level 1: 256x256 -> ye1 (128x128). 8 stripes.
  klift_fused<2, 16, 1, 0><<<dim3(8, NIMG), 256, 0, stream>>>(
      buf0, buf1, px, ux, cx, rx, py, uy, cy, ry, partial, hist_img, hist_delta);
  // levels 2-4 fused in LDS (stats only)
  klift_tail<<<NIMG, 256, 0, stream>>>(buf1, px, ux, cx, rx, py, cy, ry,
                                       partial, hist_delta);
  kfinal<<<1, 256, 0, stream>>>(partial, hist_img, hist_delta, out);
}

// Round 7
// 109.215 us; speedup vs baseline: 2.1499x; 1.2491x over previous
//
#include <hip/hip_runtime.h>
#include <math.h>

#define NIMG 96
#define NSLOT 1024
#define RES_INV (1.0f / 262144.0f)   // 1 / (512*512)

// exact fmod(v+1,2)-1 for our range
__device__ __forceinline__ float wrap1(float v) {
  float t = v + 1.0f;
  return t - 2.0f * truncf(t * 0.5f) - 1.0f;
}
__device__ __forceinline__ int bin_of(float v) {
  float b = floorf((v + 1.0f) * 128.0f);
  b = fminf(fmaxf(b, 0.0f), 255.0f);
  return (int)b;
}

// ---------------- Fused per-level kernel ------------------------------------
// x-lift in registers+shuffles (wave per row) -> LDS tile (XOR-swizzled for
// P=4 to kill the stride-4 b128 write conflict); y-lift per thread-column in
// REGISTERS: read window once from LDS, 4 unrolled independent-FMA steps,
// stats+store from regs. Validity shrinks 1 pair-row/side/step; 4-pair-row
// halos keep the interior exact; outside-image rows are zeros = reference pad.
// src: (NIMG, H, 2*W2); ye_out: (NIMG, H2, W2). W2 = H2 = 64*P.
template<int P, int SEGP, int USE_UY, int DO_IMG>
__global__ void __launch_bounds__(256) klift_fused(
    const float* __restrict__ src, float* __restrict__ ye_out,
    const float* __restrict__ kpx, const float* __restrict__ kux,
    const float* __restrict__ kcx, const float* __restrict__ krx,
    const float* __restrict__ kpy, const float* __restrict__ kuy,
    const float* __restrict__ kcy, const float* __restrict__ kry,
    double* __restrict__ partial,
    unsigned* __restrict__ hist_img, unsigned* __restrict__ hist_delta)
{
  constexpr int W2 = 64 * P;          // pairs per row = out width
  constexpr int H2 = W2;              // pair-rows in image (square levels)
  constexpr int H  = 2 * H2;          // input rows
  constexpr int NP = SEGP + 8;        // LDS pair-rows (4 halo each side)
  constexpr int NR = 2 * NP;          // LDS input rows
  __shared__ float tile[NR][W2];
  __shared__ unsigned shd[256];
  __shared__ unsigned shi[256];

  const int t = threadIdx.x, w = t >> 6, lane = t & 63;
  const int img = blockIdx.y;
  const int R0 = blockIdx.x * SEGP;        // first interior pair-row
  const int Rend = (R0 + SEGP < H2) ? R0 + SEGP : H2;
  const int base_in = 2 * R0 - 8;          // input row of LDS row 0

  shd[t] = 0;
  if (DO_IMG) shi[t] = 0;
  __syncthreads();

  const float px0 = kpx[0], px1 = kpx[1], px2 = kpx[2];
  const float ux0 = kux[0], ux1 = kux[1], ux2 = kux[2];
  const float cx0 = kcx[0], cx1 = kcx[1], cx2 = kcx[2];
  const float rx0 = krx[0], rx1 = krx[1], rx2 = krx[2];
  const float py0 = kpy[0], py1 = kpy[1], py2 = kpy[2];
  const float uy0 = kuy[0], uy1 = kuy[1], uy2 = kuy[2];
  const float cy0 = kcy[0], cy1 = kcy[1], cy2 = kcy[2];
  const float ry0 = kry[0], ry1 = kry[1], ry2 = kry[2];

  const float* ip = src + (size_t)img * H * (2 * W2);
  float sqi = 0.f, sqd = 0.f;

  auto stepm = [&](float (&d)[P], float (&s)[P], float k0, float k1, float k2, float sgn) {
    float L = __shfl_up(s[P - 1], 1); if (lane == 0) L = 0.f;
    float R = __shfl_down(s[0], 1);   if (lane == 63) R = 0.f;
    float prev = L;
#pragma unroll
    for (int j = 0; j < P; j++) {
      float nxt = (j == P - 1) ? R : s[(j + 1) < P ? (j + 1) : 0];
      d[j] += sgn * (k0 * prev + k1 * s[j] + k2 * nxt);
      prev = s[j];
    }
  };
  auto ldrow = [&](int lr, float4& A, float4& B) {
    const int gin = base_in + lr;
    if (gin >= 0 && gin < H) {
      const float* rp = ip + (size_t)gin * (2 * W2) + lane * (2 * P);
      A = *(const float4*)rp;
      if (P == 4) B = *(const float4*)(rp + 4);
    } else {
      A = make_float4(0.f, 0.f, 0.f, 0.f);
      B = make_float4(0.f, 0.f, 0.f, 0.f);
    }
  };

  // swizzled write column (P=4 only): 16B chunk c -> c ^ ((c>>3)&7)
  const int wcol = (P == 4) ? ((lane ^ ((lane >> 3) & 7)) * 4) : (lane * 2);

  // ---- x phase: wave w handles LDS rows w, w+4, ... (one full row each) ----
  float4 cA, cB, nA, nB;
  ldrow(w, cA, cB);
  for (int lr = w; lr < NR; lr += 4) {
    if (lr + 4 < NR) ldrow(lr + 4, nA, nB);
    const int gin = base_in + lr;
    const bool owned = (gin >= 2 * R0) && (gin < 2 * Rend);
    float e[P], o[P];
    e[0] = cA.x; o[0] = cA.y;
    if (P >= 2) { e[P > 1 ? 1 : 0] = cA.z; o[P > 1 ? 1 : 0] = cA.w; }
    if (P == 4) {
      e[P > 2 ? 2 : 0] = cB.x; o[P > 2 ? 2 : 0] = cB.y;
      e[P > 3 ? 3 : 0] = cB.z; o[P > 3 ? 3 : 0] = cB.w;
    }
    if (DO_IMG && owned) {
#pragma unroll
      for (int j = 0; j < P; j++) {
        sqi += e[j] * e[j] + o[j] * o[j];
        atomicAdd(&shi[bin_of(e[j])], 1u);
        atomicAdd(&shi[bin_of(o[j])], 1u);
      }
    }
    stepm(o, e, px0, px1, px2, -1.f);
    stepm(e, o, ux0, ux1, ux2,  1.f);
    stepm(o, e, cx0, cx1, cx2, -1.f);
    stepm(e, o, rx0, rx1, rx2,  1.f);
    if (P == 4) {
      *(float4*)&tile[lr][wcol] =
          make_float4(e[0], e[P > 1 ? 1 : 0], e[P > 2 ? 2 : 0], e[P > 3 ? 3 : 0]);
    } else {
      *(float2*)&tile[lr][wcol] = make_float2(e[0], e[P > 1 ? 1 : 0]);
    }
    if (owned) {
#pragma unroll
      for (int j = 0; j < P; j++) {
        float d = wrap1(o[j]);
        sqd += d * d;
        if (d >= -1.f && d <= 1.f) atomicAdd(&shd[bin_of(d)], 1u);
      }
    }
    cA = nA; cB = nB;
  }
  __syncthreads();

  // ---- y phase: register-column lifting ------------------------------------
  {
    constexpr int NSP = 256 / W2;            // column splits (1 for P=4, 2 for P=2)
    constexpr int LEN = SEGP / NSP;          // interior pair-rows per thread
    constexpr int WIN = LEN + 8;             // window pair-rows per thread
    const int col = t % W2;
    const int half = t / W2;
    const int q0 = half * LEN;               // local window start (pair-rows)
    int colr;
    if (P == 4) {
      const int ch = (col >> 2) ^ ((col >> 5) & 7);
      colr = (ch << 2) | (col & 3);
    } else colr = col;

    float ee[WIN], oo[WIN];
#pragma unroll
    for (int q = 0; q < WIN; ++q) {
      ee[q] = tile[2 * (q0 + q)][colr];
      oo[q] = tile[2 * (q0 + q) + 1][colr];
    }
    // step 1: yo -= conv(ye, py)
#pragma unroll
    for (int q = 0; q < WIN; ++q) {
      float U = (q > 0) ? ee[q - 1] : 0.f;
      float D = (q < WIN - 1) ? ee[q + 1] : 0.f;
      oo[q] -= py0 * U + py1 * ee[q] + py2 * D;
    }
    // step 2: ye += conv(yo, uy)
    if (USE_UY) {
#pragma unroll
      for (int q = 0; q < WIN; ++q) {
        float U = (q > 0) ? oo[q - 1] : 0.f;
        float D = (q < WIN - 1) ? oo[q + 1] : 0.f;
        ee[q] += uy0 * U + uy1 * oo[q] + uy2 * D;
      }
    }
    // step 3: yo -= conv(ye, cy)
#pragma unroll
    for (int q = 0; q < WIN; ++q) {
      float U = (q > 0) ? ee[q - 1] : 0.f;
      float D = (q < WIN - 1) ? ee[q + 1] : 0.f;
      oo[q] -= cy0 * U + cy1 * ee[q] + cy2 * D;
    }
    // step 4: ye += conv(yo, ry)
#pragma unroll
    for (int q = 0; q < WIN; ++q) {
      float U = (q > 0) ? oo[q - 1] : 0.f;
      float D = (q < WIN - 1) ? oo[q + 1] : 0.f;
      ee[q] += ry0 * U + ry1 * oo[q] + ry2 * D;
    }
    // stats (yo) + store (ye), interior rows only
    float* outp = ye_out + (size_t)img * H2 * W2 + col;
#pragma unroll
    for (int q = 4; q < 4 + LEN; ++q) {
      const int g = R0 + q0 + q - 4;
      float d = wrap1(oo[q]);
      sqd += d * d;
      if (d >= -1.f && d <= 1.f) atomicAdd(&shd[bin_of(d)], 1u);
      outp[(size_t)g * W2] = ee[q];
    }
  }

  // ---- reduce + flush ----
  for (int off = 32; off; off >>= 1) {
    sqd += __shfl_down(sqd, off);
    if (DO_IMG) sqi += __shfl_down(sqi, off);
  }
  if (lane == 0) {
    const int bid = blockIdx.x + blockIdx.y * gridDim.x;
    const int slot = (bid * 4 + w) & (NSLOT - 1);
    atomicAdd(&partial[NSLOT + slot], (double)sqd);
    if (DO_IMG) atomicAdd(&partial[slot], (double)sqi);
  }
  __syncthreads();
  unsigned hd = shd[t];
  if (hd) atomicAdd(&hist_delta[img * 256 + t], hd);
  if (DO_IMG) {
    unsigned hi = shi[t];
    if (hi) atomicAdd(&hist_img[img * 256 + t], hi);
  }
}

// ---------------- Kernel C: fused tail, levels 2-4 in LDS, 1 block = 1 image
// src: (NIMG,128,128). In-place strided wavelet. Stats only.
// uy is NOT applied at lvl>=2, so py and cy steps merge: yo -= conv(ye, py+cy).
__global__ void __launch_bounds__(256) klift_tail(
    const float* __restrict__ src,
    const float* __restrict__ kpx, const float* __restrict__ kux,
    const float* __restrict__ kcx, const float* __restrict__ krx,
    const float* __restrict__ kpy, const float* __restrict__ kcy,
    const float* __restrict__ kry,
    double* __restrict__ partial, unsigned* __restrict__ hist_delta)
{
  __shared__ float tile[128][129];
  __shared__ unsigned shd[256];
  const int t = threadIdx.x;
  const int img = blockIdx.x;
  shd[t] = 0;

  const float* sp = src + (size_t)img * 128 * 128;
  for (int idx = t; idx < 128 * 32; idx += 256) {
    const int r = idx >> 5, c4 = (idx & 31) << 2;
    float4 v = *(const float4*)(sp + r * 128 + c4);
    tile[r][c4] = v.x; tile[r][c4 + 1] = v.y;
    tile[r][c4 + 2] = v.z; tile[r][c4 + 3] = v.w;
  }
  const float px0 = kpx[0], px1 = kpx[1], px2 = kpx[2];
  const float ux0 = kux[0], ux1 = kux[1], ux2 = kux[2];
  const float cx0 = kcx[0], cx1 = kcx[1], cx2 = kcx[2];
  const float rx0 = krx[0], rx1 = krx[1], rx2 = krx[2];
  const float pc0 = kpy[0] + kcy[0], pc1 = kpy[1] + kcy[1], pc2 = kpy[2] + kcy[2];
  const float ry0 = kry[0], ry1 = kry[1], ry2 = kry[2];
  float sqd = 0.f;
  __syncthreads();

  for (int l = 0; l < 3; ++l) {
    const int s = 1 << l, n = 128 >> l, half = n >> 1;
    const int totx = n * half;

    for (int idx = t; idx < totx; idx += 256) {
      const int r = (idx / half) * s, c = idx % half;
      float L = (c > 0) ? tile[r][(2 * c - 2) * s] : 0.f;
      float M = tile[r][2 * c * s];
      float R = (c < half - 1) ? tile[r][(2 * c + 2) * s] : 0.f;
      tile[r][(2 * c + 1) * s] -= px0 * L + px1 * M + px2 * R;
    }
    __syncthreads();
    for (int idx = t; idx < totx; idx += 256) {
      const int r = (idx / half) * s, c = idx % half;
      float L = (c > 0) ? tile[r][(2 * c - 1) * s] : 0.f;
      float M = tile[r][(2 * c + 1) * s];
      float R = (c < half - 1) ? tile[r][(2 * c + 3) * s] : 0.f;
      tile[r][2 * c * s] += ux0 * L + ux1 * M + ux2 * R;
    }
    __syncthreads();
    for (int idx = t; idx < totx; idx += 256) {
      const int r = (idx / half) * s, c = idx % half;
      float L = (c > 0) ? tile[r][(2 * c - 2) * s] : 0.f;
      float M = tile[r][2 * c * s];
      float R = (c < half - 1) ? tile[r][(2 * c + 2) * s] : 0.f;
      tile[r][(2 * c + 1) * s] -= cx0 * L + cx1 * M + cx2 * R;
    }
    __syncthreads();
    for (int idx = t; idx < totx; idx += 256) {
      const int r = (idx / half) * s, c = idx % half;
      float L = (c > 0) ? tile[r][(2 * c - 1) * s] : 0.f;
      float M = tile[r][(2 * c + 1) * s];
      float R = (c < half - 1) ? tile[r][(2 * c + 3) * s] : 0.f;
      tile[r][2 * c * s] += rx0 * L + rx1 * M + rx2 * R;
    }
    __syncthreads();
    for (int idx = t; idx < totx; idx += 256) {
      const int r = (idx / half) * s, c = idx % half;
      float d = wrap1(tile[r][(2 * c + 1) * s]);
      sqd += d * d;
      if (d >= -1.f && d <= 1.f) atomicAdd(&shd[bin_of(d)], 1u);
    }
    const int toty = half * half;
    for (int idx = t; idx < toty; idx += 256) {
      const int r = idx / half, j = idx % half, col = j * 2 * s;
      float U = (r > 0) ? tile[(2 * r - 2) * s][col] : 0.f;
      float M = tile[(2 * r) * s][col];
      float D = (r < half - 1) ? tile[(2 * r + 2) * s][col] : 0.f;
      tile[(2 * r + 1) * s][col] -= pc0 * U + pc1 * M + pc2 * D;
    }
    __syncthreads();
    for (int idx = t; idx < toty; idx += 256) {
      const int r = idx / half, j = idx % half, col = j * 2 * s;
      float U = (r > 0) ? tile[(2 * r - 1) * s][col] : 0.f;
      float M = tile[(2 * r + 1) * s][col];
      float D = (r < half - 1) ? tile[(2 * r + 3) * s][col] : 0.f;
      tile[(2 * r) * s][col] += ry0 * U + ry1 * M + ry2 * D;
    }
    __syncthreads();
    for (int idx = t; idx < toty; idx += 256) {
      const int r = idx / half, j = idx % half, col = j * 2 * s;
      float d = wrap1(tile[(2 * r + 1) * s][col]);
      sqd += d * d;
      if (d >= -1.f && d <= 1.f) atomicAdd(&shd[bin_of(d)], 1u);
      if (l == 2) {
        float d2 = wrap1(tile[(2 * r) * s][col]);
        sqd += d2 * d2;
        if (d2 >= -1.f && d2 <= 1.f) atomicAdd(&shd[bin_of(d2)], 1u);
      }
    }
    __syncthreads();
  }

  for (int off = 32; off; off >>= 1) sqd += __shfl_down(sqd, off);
  __shared__ float swv[4];
  if ((t & 63) == 0) swv[t >> 6] = sqd;
  __syncthreads();
  if (t == 0) {
    double tot = (double)swv[0] + swv[1] + swv[2] + swv[3];
    atomicAdd(&partial[NSLOT + (img & (NSLOT - 1))], tot);
  }
  unsigned hd = shd[t];
  if (hd) atomicAdd(&hist_delta[img * 256 + t], hd);
}

// ---------------- Final reduction: entropies + losses -----------------------
__global__ void __launch_bounds__(256) kfinal(
    const double* __restrict__ partial,
    const unsigned* __restrict__ hist_img,
    const unsigned* __restrict__ hist_delta,
    float* __restrict__ out)
{
  __shared__ double sI[256], sD[256], sPi[256], sPd[256];
  const int t = threadIdx.x;
  double entI = 0.0, entD = 0.0;
  for (int img = 0; img < NIMG; ++img) {
    unsigned ci = hist_img[img * 256 + t];
    if (ci) { float p = (float)ci * RES_INV; entI += (double)(-p * log2f(p)); }
    unsigned cd = hist_delta[img * 256 + t];
    if (cd) { float p = (float)cd * RES_INV; entD += (double)(-p * log2f(p)); }
  }
  double pi = 0.0, pd = 0.0;
  for (int s = t; s < NSLOT; s += 256) {
    pi += partial[s];
    pd += partial[NSLOT + s];
  }
  sI[t] = entI; sD[t] = entD; sPi[t] = pi; sPd[t] = pd;
  __syncthreads();
  for (int s = 128; s; s >>= 1) {
    if (t < s) {
      sI[t] += sI[t + s]; sD[t] += sD[t + s];
      sPi[t] += sPi[t + s]; sPd[t] += sPd[t + s];
    }
    __syncthreads();
  }
  if (t == 0) {
    const double tot = (double)NIMG * 262144.0;
    out[0] = (float)(255.0 * sqrt(sPd[0] / tot));  // loss1 (deltas)
    out[1] = (float)(255.0 * sqrt(sPi[0] / tot));  // loss0 (img)
    out[2] = (float)(sI[0] / (8.0 * NIMG));        // invCR0
    out[3] = (float)(sD[0] / (8.0 * NIMG));        // invCR1
  }
}

extern "C" void kernel_launch(void* const* d_in, const int* in_sizes, int n_in,
                              void* d_out, int out_size, void* d_ws, size_t ws_size,
                              hipStream_t stream)
{
  const float* x  = (const float*)d_in[0];
  const float* px = (const float*)d_in[1];
  const float* ux = (const float*)d_in[2];
  const float* cx = (const float*)d_in[3];
  const float* rx = (const float*)d_in[4];
  const float* py = (const float*)d_in[5];
  const float* uy = (const float*)d_in[6];
  const float* cy = (const float*)d_in[7];
  const float* ry = (const float*)d_in[8];
  float* out = (float*)d_out;

  char* ws = (char*)d_ws;
  double*   partial    = (double*)ws;
  unsigned* hist_img   = (unsigned*)(ws + 2 * NSLOT * 8);
  unsigned* hist_delta = (unsigned*)(ws + 2 * NSLOT * 8 + NIMG * 256 * 4);
  float* buf0 = (float*)(ws + (1 << 18));                        // ye0: 25.2MB
  float* buf1 = (float*)(ws + (1 << 18) + ((size_t)32 << 20));   // ye1: 6.3MB

  hipMemsetAsync(ws, 0, 2 * NSLOT * 8 + 2 * NIMG * 256 * 4, stream);

  // level 0: 512x512 -> ye0 (256x256), img+delta stats. 16 stripes of 16 pair-rows.
  klift_fused<4, 16, 1, 1><<<dim3(16, NIMG), 256, 0, stream>>>(
      x, buf0, px, ux, cx, rx, py, uy, cy, ry, partial, hist_img, hist_delta);
  // level 1: 256x256 -> ye1 (128x128). 8 stripes, 2 column-splits.
  klift_fused<2, 16, 1, 0><<<dim3(8, NIMG), 256, 0, stream>>>(
      buf0, buf1, px, ux, cx, rx, py, uy, cy, ry, partial, hist_img, hist_delta);
  // levels 2-4 fused in LDS (stats only)
  klift_tail<<<NIMG, 256, 0, stream>>>(buf1, px, ux, cx, rx, py, cy, ry,
                                       partial, hist_delta);
  kfinal<<<1, 256, 0, stream>>>(partial, hist_img, hist_delta, out);
}

// Round 8
// 89.261 us; speedup vs baseline: 2.6305x; 1.2236x over previous
//
#include <hip/hip_runtime.h>
#include <math.h>

#define NIMG 96
#define NSLOT 1024
#define RES_INV (1.0f / 262144.0f)   // 1 / (512*512)

// exact fmod(v+1,2)-1 for our range (matches reference rounding exactly)
__device__ __forceinline__ float wrap1(float v) {
  float t = v + 1.0f;
  return t - 2.0f * truncf(t * 0.5f) - 1.0f;
}
// bin for v in [-1,1): floor(fl(v+1)*128) == single-rounded fma (pow2 scale
// commutes with rounding); clamp 255 for the (v+1)*128 -> 256.0 rounding edge.
__device__ __forceinline__ int bin_fast(float v) {
  int b = (int)fmaf(v, 128.0f, 128.0f);
  return (b > 255) ? 255 : b;
}

// ---------------- Fused per-level kernel ------------------------------------
// x-lift in registers+shuffles (wave per row) -> LDS tile (XOR-swizzled for
// P=4); y-lift per thread-column in registers (window read once, 4 unrolled
// steps). Validity shrinks 1 pair-row/side/step; 4-pair-row halos keep the
// interior exact; outside-image rows are zeros = reference zero-pad.
// src: (NIMG, H, 2*W2); ye_out: (NIMG, H2, W2). W2 = H2 = 64*P.
template<int P, int SEGP, int USE_UY, int DO_IMG>
__global__ void __launch_bounds__(256) klift_fused(
    const float* __restrict__ src, float* __restrict__ ye_out,
    const float* __restrict__ kpx, const float* __restrict__ kux,
    const float* __restrict__ kcx, const float* __restrict__ krx,
    const float* __restrict__ kpy, const float* __restrict__ kuy,
    const float* __restrict__ kcy, const float* __restrict__ kry,
    double* __restrict__ partial,
    unsigned* __restrict__ hist_img, unsigned* __restrict__ hist_delta)
{
  constexpr int W2 = 64 * P;          // pairs per row = out width
  constexpr int H2 = W2;              // pair-rows in image (square levels)
  constexpr int H  = 2 * H2;          // input rows
  constexpr int NP = SEGP + 8;        // LDS pair-rows (4 halo each side)
  constexpr int NR = 2 * NP;          // LDS input rows
  constexpr int NITER = NR / 4;       // x-rows per wave
  __shared__ float tile[NR][W2];
  __shared__ unsigned shd[256];
  __shared__ unsigned shi[256];

  const int t = threadIdx.x, w = t >> 6, lane = t & 63;
  const int img = blockIdx.y;
  const int R0 = blockIdx.x * SEGP;        // first interior pair-row
  const int base_in = 2 * R0 - 8;          // input row of LDS row 0

  shd[t] = 0;
  if (DO_IMG) shi[t] = 0;
  __syncthreads();

  const float px0 = kpx[0], px1 = kpx[1], px2 = kpx[2];
  const float ux0 = kux[0], ux1 = kux[1], ux2 = kux[2];
  const float cx0 = kcx[0], cx1 = kcx[1], cx2 = kcx[2];
  const float rx0 = krx[0], rx1 = krx[1], rx2 = krx[2];
  const float py0 = kpy[0], py1 = kpy[1], py2 = kpy[2];
  const float uy0 = kuy[0], uy1 = kuy[1], uy2 = kuy[2];
  const float cy0 = kcy[0], cy1 = kcy[1], cy2 = kcy[2];
  const float ry0 = kry[0], ry1 = kry[1], ry2 = kry[2];

  const float* ip = src + (size_t)img * H * (2 * W2);
  float sqi = 0.f, sqd = 0.f;

  auto stepm = [&](float (&d)[P], float (&s)[P], float k0, float k1, float k2, float sgn) {
    float L = __shfl_up(s[P - 1], 1); if (lane == 0) L = 0.f;
    float R = __shfl_down(s[0], 1);   if (lane == 63) R = 0.f;
    float prev = L;
#pragma unroll
    for (int j = 0; j < P; j++) {
      float nxt = (j == P - 1) ? R : s[(j + 1) < P ? (j + 1) : 0];
      d[j] += sgn * (k0 * prev + k1 * s[j] + k2 * nxt);
      prev = s[j];
    }
  };
  auto ldrow = [&](int lr, float4& A, float4& B, bool chk) {
    const int gin = base_in + lr;
    if (!chk || ((unsigned)gin < (unsigned)H)) {
      const float* rp = ip + (size_t)gin * (2 * W2) + lane * (2 * P);
      if (P == 1) { float2 v = *(const float2*)rp; A.x = v.x; A.y = v.y; }
      else {
        A = *(const float4*)rp;
        if (P == 4) B = *(const float4*)(rp + 4);
      }
    } else {
      A = make_float4(0.f, 0.f, 0.f, 0.f);
      B = make_float4(0.f, 0.f, 0.f, 0.f);
    }
  };

  // swizzled write column (P=4 only): 16B chunk c -> c ^ ((c>>3)&7)
  const int wcol = (P == 4) ? ((lane ^ ((lane >> 3) & 7)) * 4)
                 : (P == 2) ? (lane * 2) : lane;

  // ---- x phase: wave w handles LDS rows w, w+4, ...; fully unrolled so the
  // owned/halo split is compile-time ----
  float4 cA = make_float4(0.f,0.f,0.f,0.f), cB = cA, nA = cA, nB = cA;
  ldrow(w, cA, cB, true);
#pragma unroll
  for (int i = 0; i < NITER; ++i) {
    const int lr = w + 4 * i;
    if (i + 1 < NITER)
      ldrow(lr + 4, nA, nB, (i + 1 < 2) || (i + 1 >= NITER - 2));
    const bool owned = (i >= 2) && (i < NITER - 2);   // compile-time
    float e[P], o[P];
    e[0] = cA.x; o[0] = cA.y;
    if (P >= 2) { e[P > 1 ? 1 : 0] = cA.z; o[P > 1 ? 1 : 0] = cA.w; }
    if (P == 4) {
      e[P > 2 ? 2 : 0] = cB.x; o[P > 2 ? 2 : 0] = cB.y;
      e[P > 3 ? 3 : 0] = cB.z; o[P > 3 ? 3 : 0] = cB.w;
    }
    if (DO_IMG && owned) {
#pragma unroll
      for (int j = 0; j < P; j++) {
        sqi += e[j] * e[j] + o[j] * o[j];
        atomicAdd(&shi[bin_fast(e[j])], 1u);
        atomicAdd(&shi[bin_fast(o[j])], 1u);
      }
    }
    stepm(o, e, px0, px1, px2, -1.f);
    stepm(e, o, ux0, ux1, ux2,  1.f);
    stepm(o, e, cx0, cx1, cx2, -1.f);
    stepm(e, o, rx0, rx1, rx2,  1.f);
    if (P == 4) {
      *(float4*)&tile[lr][wcol] =
          make_float4(e[0], e[P > 1 ? 1 : 0], e[P > 2 ? 2 : 0], e[P > 3 ? 3 : 0]);
    } else if (P == 2) {
      *(float2*)&tile[lr][wcol] = make_float2(e[0], e[P > 1 ? 1 : 0]);
    } else {
      tile[lr][wcol] = e[0];
    }
    if (owned) {
#pragma unroll
      for (int j = 0; j < P; j++) {
        float d = wrap1(o[j]);
        sqd += d * d;
        atomicAdd(&shd[bin_fast(d)], 1u);
      }
    }
    cA = nA; cB = nB;
  }
  __syncthreads();

  // ---- y phase: register-column lifting ------------------------------------
  {
    constexpr int NSP = 256 / W2;            // column splits
    constexpr int LEN = SEGP / NSP;          // interior pair-rows per thread
    constexpr int WIN = LEN + 8;             // window pair-rows per thread
    const int col = t % W2;
    const int half = t / W2;
    const int q0 = half * LEN;               // local window start (pair-rows)
    int colr;
    if (P == 4) {
      const int ch = (col >> 2) ^ ((col >> 5) & 7);
      colr = (ch << 2) | (col & 3);
    } else colr = col;

    float ee[WIN], oo[WIN];
#pragma unroll
    for (int q = 0; q < WIN; ++q) {
      ee[q] = tile[2 * (q0 + q)][colr];
      oo[q] = tile[2 * (q0 + q) + 1][colr];
    }
#pragma unroll
    for (int q = 0; q < WIN; ++q) {
      float U = (q > 0) ? ee[q - 1] : 0.f;
      float D = (q < WIN - 1) ? ee[q + 1] : 0.f;
      oo[q] -= py0 * U + py1 * ee[q] + py2 * D;
    }
    if (USE_UY) {
#pragma unroll
      for (int q = 0; q < WIN; ++q) {
        float U = (q > 0) ? oo[q - 1] : 0.f;
        float D = (q < WIN - 1) ? oo[q + 1] : 0.f;
        ee[q] += uy0 * U + uy1 * oo[q] + uy2 * D;
      }
    }
#pragma unroll
    for (int q = 0; q < WIN; ++q) {
      float U = (q > 0) ? ee[q - 1] : 0.f;
      float D = (q < WIN - 1) ? ee[q + 1] : 0.f;
      oo[q] -= cy0 * U + cy1 * ee[q] + cy2 * D;
    }
#pragma unroll
    for (int q = 0; q < WIN; ++q) {
      float U = (q > 0) ? oo[q - 1] : 0.f;
      float D = (q < WIN - 1) ? oo[q + 1] : 0.f;
      ee[q] += ry0 * U + ry1 * oo[q] + ry2 * D;
    }
    float* outp = ye_out + (size_t)img * H2 * W2 + col;
#pragma unroll
    for (int q = 4; q < 4 + LEN; ++q) {
      const int g = R0 + q0 + q - 4;
      float d = wrap1(oo[q]);
      sqd += d * d;
      atomicAdd(&shd[bin_fast(d)], 1u);
      outp[(size_t)g * W2] = ee[q];
    }
  }

  // ---- reduce + flush ----
  for (int off = 32; off; off >>= 1) {
    sqd += __shfl_down(sqd, off);
    if (DO_IMG) sqi += __shfl_down(sqi, off);
  }
  if (lane == 0) {
    const int bid = blockIdx.x + blockIdx.y * gridDim.x;
    const int slot = (bid * 4 + w) & (NSLOT - 1);
    atomicAdd(&partial[NSLOT + slot], (double)sqd);
    if (DO_IMG) atomicAdd(&partial[slot], (double)sqi);
  }
  __syncthreads();
  unsigned hd = shd[t];
  if (hd) atomicAdd(&hist_delta[img * 256 + t], hd);
  if (DO_IMG) {
    unsigned hi = shi[t];
    if (hi) atomicAdd(&hist_img[img * 256 + t], hi);
  }
}

// ---------------- Tail: levels 3-4 on 64x64 in LDS, 1 block = 1 image -------
// uy is NOT applied at lvl>=2, so py and cy steps merge: yo -= conv(ye, py+cy).
__global__ void __launch_bounds__(256) klift_tail64(
    const float* __restrict__ src,
    const float* __restrict__ kpx, const float* __restrict__ kux,
    const float* __restrict__ kcx, const float* __restrict__ krx,
    const float* __restrict__ kpy, const float* __restrict__ kcy,
    const float* __restrict__ kry,
    double* __restrict__ partial, unsigned* __restrict__ hist_delta)
{
  __shared__ float tile[64][65];
  __shared__ unsigned shd[256];
  const int t = threadIdx.x;
  const int img = blockIdx.x;
  shd[t] = 0;

  const float* sp = src + (size_t)img * 64 * 64;
  for (int idx = t; idx < 64 * 16; idx += 256) {
    const int r = idx >> 4, c4 = (idx & 15) << 2;
    float4 v = *(const float4*)(sp + r * 64 + c4);
    tile[r][c4] = v.x; tile[r][c4 + 1] = v.y;
    tile[r][c4 + 2] = v.z; tile[r][c4 + 3] = v.w;
  }
  const float px0 = kpx[0], px1 = kpx[1], px2 = kpx[2];
  const float ux0 = kux[0], ux1 = kux[1], ux2 = kux[2];
  const float cx0 = kcx[0], cx1 = kcx[1], cx2 = kcx[2];
  const float rx0 = krx[0], rx1 = krx[1], rx2 = krx[2];
  const float pc0 = kpy[0] + kcy[0], pc1 = kpy[1] + kcy[1], pc2 = kpy[2] + kcy[2];
  const float ry0 = kry[0], ry1 = kry[1], ry2 = kry[2];
  float sqd = 0.f;
  __syncthreads();

  for (int l = 0; l < 2; ++l) {
    const int s = 1 << l, n = 64 >> l, half = n >> 1;
    const int totx = n * half;

    for (int idx = t; idx < totx; idx += 256) {
      const int r = (idx / half) * s, c = idx % half;
      float L = (c > 0) ? tile[r][(2 * c - 2) * s] : 0.f;
      float M = tile[r][2 * c * s];
      float R = (c < half - 1) ? tile[r][(2 * c + 2) * s] : 0.f;
      tile[r][(2 * c + 1) * s] -= px0 * L + px1 * M + px2 * R;
    }
    __syncthreads();
    for (int idx = t; idx < totx; idx += 256) {
      const int r = (idx / half) * s, c = idx % half;
      float L = (c > 0) ? tile[r][(2 * c - 1) * s] : 0.f;
      float M = tile[r][(2 * c + 1) * s];
      float R = (c < half - 1) ? tile[r][(2 * c + 3) * s] : 0.f;
      tile[r][2 * c * s] += ux0 * L + ux1 * M + ux2 * R;
    }
    __syncthreads();
    for (int idx = t; idx < totx; idx += 256) {
      const int r = (idx / half) * s, c = idx % half;
      float L = (c > 0) ? tile[r][(2 * c - 2) * s] : 0.f;
      float M = tile[r][2 * c * s];
      float R = (c < half - 1) ? tile[r][(2 * c + 2) * s] : 0.f;
      tile[r][(2 * c + 1) * s] -= cx0 * L + cx1 * M + cx2 * R;
    }
    __syncthreads();
    for (int idx = t; idx < totx; idx += 256) {
      const int r = (idx / half) * s, c = idx % half;
      float L = (c > 0) ? tile[r][(2 * c - 1) * s] : 0.f;
      float M = tile[r][(2 * c + 1) * s];
      float R = (c < half - 1) ? tile[r][(2 * c + 3) * s] : 0.f;
      tile[r][2 * c * s] += rx0 * L + rx1 * M + rx2 * R;
    }
    __syncthreads();
    for (int idx = t; idx < totx; idx += 256) {
      const int r = (idx / half) * s, c = idx % half;
      float d = wrap1(tile[r][(2 * c + 1) * s]);
      sqd += d * d;
      atomicAdd(&shd[bin_fast(d)], 1u);
    }
    const int toty = half * half;
    for (int idx = t; idx < toty; idx += 256) {
      const int r = idx / half, j = idx % half, col = j * 2 * s;
      float U = (r > 0) ? tile[(2 * r - 2) * s][col] : 0.f;
      float M = tile[(2 * r) * s][col];
      float D = (r < half - 1) ? tile[(2 * r + 2) * s][col] : 0.f;
      tile[(2 * r + 1) * s][col] -= pc0 * U + pc1 * M + pc2 * D;
    }
    __syncthreads();
    for (int idx = t; idx < toty; idx += 256) {
      const int r = idx / half, j = idx % half, col = j * 2 * s;
      float U = (r > 0) ? tile[(2 * r - 1) * s][col] : 0.f;
      float M = tile[(2 * r + 1) * s][col];
      float D = (r < half - 1) ? tile[(2 * r + 3) * s][col] : 0.f;
      tile[(2 * r) * s][col] += ry0 * U + ry1 * M + ry2 * D;
    }
    __syncthreads();
    for (int idx = t; idx < toty; idx += 256) {
      const int r = idx / half, j = idx % half, col = j * 2 * s;
      float d = wrap1(tile[(2 * r + 1) * s][col]);
      sqd += d * d;
      atomicAdd(&shd[bin_fast(d)], 1u);
      if (l == 1) {
        float d2 = wrap1(tile[(2 * r) * s][col]);
        sqd += d2 * d2;
        atomicAdd(&shd[bin_fast(d2)], 1u);
      }
    }
    __syncthreads();
  }

  for (int off = 32; off; off >>= 1) sqd += __shfl_down(sqd, off);
  __shared__ float swv[4];
  if ((t & 63) == 0) swv[t >> 6] = sqd;
  __syncthreads();
  if (t == 0) {
    double tot = (double)swv[0] + swv[1] + swv[2] + swv[3];
    atomicAdd(&partial[NSLOT + (img & (NSLOT - 1))], tot);
  }
  unsigned hd = shd[t];
  if (hd) atomicAdd(&hist_delta[img * 256 + t], hd);
}

// ---------------- Final reduction: entropies + losses -----------------------
__global__ void __launch_bounds__(256) kfinal(
    const double* __restrict__ partial,
    const unsigned* __restrict__ hist_img,
    const unsigned* __restrict__ hist_delta,
    float* __restrict__ out)
{
  __shared__ double sI[256], sD[256], sPi[256], sPd[256];
  const int t = threadIdx.x;
  double entI = 0.0, entD = 0.0;
  for (int img = 0; img < NIMG; ++img) {
    unsigned ci = hist_img[img * 256 + t];
    if (ci) { float p = (float)ci * RES_INV; entI += (double)(-p * log2f(p)); }
    unsigned cd = hist_delta[img * 256 + t];
    if (cd) { float p = (float)cd * RES_INV; entD += (double)(-p * log2f(p)); }
  }
  double pi = 0.0, pd = 0.0;
  for (int s = t; s < NSLOT; s += 256) {
    pi += partial[s];
    pd += partial[NSLOT + s];
  }
  sI[t] = entI; sD[t] = entD; sPi[t] = pi; sPd[t] = pd;
  __syncthreads();
  for (int s = 128; s; s >>= 1) {
    if (t < s) {
      sI[t] += sI[t + s]; sD[t] += sD[t + s];
      sPi[t] += sPi[t + s]; sPd[t] += sPd[t + s];
    }
    __syncthreads();
  }
  if (t == 0) {
    const double tot = (double)NIMG * 262144.0;
    out[0] = (float)(255.0 * sqrt(sPd[0] / tot));  // loss1 (deltas)
    out[1] = (float)(255.0 * sqrt(sPi[0] / tot));  // loss0 (img)
    out[2] = (float)(sI[0] / (8.0 * NIMG));        // invCR0
    out[3] = (float)(sD[0] / (8.0 * NIMG));        // invCR1
  }
}

extern "C" void kernel_launch(void* const* d_in, const int* in_sizes, int n_in,
                              void* d_out, int out_size, void* d_ws, size_t ws_size,
                              hipStream_t stream)
{
  const float* x  = (const float*)d_in[0];
  const float* px = (const float*)d_in[1];
  const float* ux = (const float*)d_in[2];
  const float* cx = (const float*)d_in[3];
  const float* rx = (const float*)d_in[4];
  const float* py = (const float*)d_in[5];
  const float* uy = (const float*)d_in[6];
  const float* cy = (const float*)d_in[7];
  const float* ry = (const float*)d_in[8];
  float* out = (float*)d_out;

  char* ws = (char*)d_ws;
  double*   partial    = (double*)ws;
  unsigned* hist_img   = (unsigned*)(ws + 2 * NSLOT * 8);
  unsigned* hist_delta = (unsigned*)(ws + 2 * NSLOT * 8 + NIMG * 256 * 4);
  float* buf0 = (float*)(ws + (1 << 20));                        // ye0: 25.2MB
  float* buf1 = (float*)(ws + (1 << 20) + ((size_t)32 << 20));   // ye1: 6.3MB
  float* buf2 = (float*)(ws + (1 << 20) + ((size_t)40 << 20));   // ye2: 1.6MB

  hipMemsetAsync(ws, 0, 2 * NSLOT * 8 + 2 * NIMG * 256 * 4, stream);

  // level 0: 512x512 -> ye0 (256x256), img+delta stats. 16 stripes.
  klift_fused<4, 16, 1, 1><<<dim3(16, NIMG), 256, 0, stream>>>(
      x, buf0, px, ux, cx, rx, py, uy, cy, ry, partial, hist_img, hist_delta);
  // level 1: 256x256 -> ye1 (128x128). 16 stripes of 8 pair-rows.
  klift_fused<2, 8, 1, 0><<<dim3(16, NIMG), 256, 0, stream>>>(
      buf0, buf1, px, ux, cx, rx, py, uy, cy, ry, partial, hist_img, hist_delta);
  // level 2: 128x128 -> ye2 (64x64), no uy. 8 stripes.
  klift_fused<1, 8, 0, 0><<<dim3(8, NIMG), 256, 0, stream>>>(
      buf1, buf2, px, ux, cx, rx, py, uy, cy, ry, partial, hist_img, hist_delta);
  // levels 3-4 in LDS (stats only)
  klift_tail64<<<NIMG, 256, 0, stream>>>(buf2, px, ux, cx, rx, py, cy, ry,
                                         partial, hist_delta);
  kfinal<<<1, 256, 0, stream>>>(partial, hist_img, hist_delta, out);
}